// Round 1
// baseline (391.267 us; speedup 1.0000x reference)
//
#include <hip/hip_runtime.h>
#include <hip/hip_bf16.h>

#define HH 64
#define WW 64
#define HWSZ 4096
#define NBATCH 4
#define CCH 256
#define NPIX 16384   // NBATCH*HWSZ
#define CK 2304      // 9*256
#define EPSB 1e-5f

typedef __attribute__((ext_vector_type(8))) short bf16x8;
typedef __attribute__((ext_vector_type(4))) float f32x4;

// ---------------- transpose x (N,C,H,W) -> xT (N,HW,C) ----------------
__global__ __launch_bounds__(256) void k_transpose_in(const float* __restrict__ x,
                                                      float* __restrict__ xT){
  __shared__ float tile[64][65];
  int hw0 = blockIdx.x * 64;
  int c0  = blockIdx.y * 64;
  int n   = blockIdx.z;
  int t = threadIdx.x;
  int col = t & 63, rb = t >> 6;
#pragma unroll
  for (int r = 0; r < 16; ++r){
    int cl = rb + r*4;
    tile[cl][col] = x[(size_t)(n*CCH + c0 + cl)*HWSZ + hw0 + col];
  }
  __syncthreads();
#pragma unroll
  for (int r = 0; r < 16; ++r){
    int hwl = rb + r*4;
    xT[(size_t)(n*HWSZ + hw0 + hwl)*CCH + c0 + col] = tile[col][hwl];
  }
}

// ---------------- permute offset-conv weights to [c][k][och6] ----------------
__global__ void k_woff_perm(const float* __restrict__ tmw, const float* __restrict__ trw,
                            float* __restrict__ woff){
  int idx = blockIdx.x*256 + threadIdx.x;
  if (idx >= CCH*54) return;
  int c = idx / 54; int rem = idx % 54; int k = rem / 6; int och = rem % 6;
  float v = (och < 4) ? tmw[(size_t)(och*CCH + c)*9 + k]
                      : trw[(size_t)((och-4)*CCH + c)*9 + k];
  woff[idx] = v;
}

// ---------------- permute dcn weights (Co,C,9) -> bf16 [o][k*256+c] ----------------
__global__ void k_wgemm_perm(const float* __restrict__ w, __hip_bfloat16* __restrict__ wp){
  int idx = blockIdx.x*256 + threadIdx.x;    // 589824 total
  if (idx >= CCH*CK) return;
  int o = idx / CK; int rem = idx % CK; int k = rem >> 8; int c = rem & 255;
  wp[idx] = __float2bfloat16(w[(size_t)(o*CCH + c)*9 + k]);
}

// ---------------- offset generation: conv3x3(6ch) + make_offset ----------------
__global__ __launch_bounds__(256) void k_offsets(const float* __restrict__ src,
    const float* __restrict__ woff, const float* __restrict__ tmb,
    const float* __restrict__ trb, float* __restrict__ off){
  __shared__ float wl[CCH*54];
  int t = threadIdx.x;
  for (int i = t; i < CCH*54; i += 256) wl[i] = woff[i];
  __syncthreads();
  int b = blockIdx.x;                         // N*H*(W/8) = 2048
  int n = b >> 9; int rem = b & 511; int h = rem >> 3; int w0 = (rem & 7) * 8;
  int pg = t >> 5, ci = t & 31;
  int w = w0 + pg;
  float acc0=0,acc1=0,acc2=0,acc3=0,acc4=0,acc5=0;
#pragma unroll
  for (int k = 0; k < 9; ++k){
    int yy = h + k/3 - 1, xx = w + k%3 - 1;
    if (yy >= 0 && yy < HH && xx >= 0 && xx < WW){
      const float* s = src + (size_t)(n*HWSZ + yy*WW + xx)*CCH + ci*8;
      float4 va = *(const float4*)s;
      float4 vb = *(const float4*)(s+4);
      float vs[8] = {va.x,va.y,va.z,va.w,vb.x,vb.y,vb.z,vb.w};
#pragma unroll
      for (int j = 0; j < 8; ++j){
        const float* wb = wl + ((ci*8 + j)*9 + k)*6;
        float v = vs[j];
        acc0 += v*wb[0]; acc1 += v*wb[1]; acc2 += v*wb[2];
        acc3 += v*wb[3]; acc4 += v*wb[4]; acc5 += v*wb[5];
      }
    }
  }
#pragma unroll
  for (int m = 16; m >= 1; m >>= 1){
    acc0 += __shfl_xor(acc0, m); acc1 += __shfl_xor(acc1, m); acc2 += __shfl_xor(acc2, m);
    acc3 += __shfl_xor(acc3, m); acc4 += __shfl_xor(acc4, m); acc5 += __shfl_xor(acc5, m);
  }
  if (ci == 0){
    float m00 = acc0 + tmb[0], m01 = acc1 + tmb[1];
    float m10 = acc2 + tmb[2], m11 = acc3 + tmb[3];
    float t0 = acc4 + trb[0], t1 = acc5 + trb[1];
    size_t p = (size_t)n*HWSZ + h*WW + w;
#pragma unroll
    for (int k = 0; k < 9; ++k){
      float dy = (float)(k/3 - 1), dx = (float)(k%3 - 1);
      off[(p*9 + k)*2 + 0] = m00*dy + m01*dx - dy + t0;
      off[(p*9 + k)*2 + 1] = m10*dy + m11*dx - dx + t1;
    }
  }
}

// ---------------- im2col with bilinear sampling -> bf16 cols [p][k*256+c] ----------------
__global__ __launch_bounds__(256) void k_im2col(const float* __restrict__ src,
    const float* __restrict__ off, __hip_bfloat16* __restrict__ cols,
    int p_start, int p_count){
  int t = threadIdx.x;
  int pb = p_start + blockIdx.x*4;
#pragma unroll
  for (int pi = 0; pi < 4; ++pi){
    int p = pb + pi;
    int n = p >> 12; int hw = p & 4095; int h = hw >> 6; int w = hw & 63;
    const float* base = src + (size_t)n*HWSZ*CCH;
#pragma unroll
    for (int k = 0; k < 9; ++k){
      float offy = off[((size_t)p*9 + k)*2 + 0];
      float offx = off[((size_t)p*9 + k)*2 + 1];
      float py = (float)(h + k/3 - 1) + offy;
      float px = (float)(w + k%3 - 1) + offx;
      float y0f = floorf(py), x0f = floorf(px);
      float wy = py - y0f, wx = px - x0f;
      int y0 = (int)y0f, x0 = (int)x0f;
      int y1 = y0 + 1, x1 = x0 + 1;
      float w00 = (1.f-wy)*(1.f-wx), w01 = (1.f-wy)*wx;
      float w10 = wy*(1.f-wx),       w11 = wy*wx;
      if (y0 < 0 || y0 >= HH) { w00 = 0.f; w01 = 0.f; }
      if (y1 < 0 || y1 >= HH) { w10 = 0.f; w11 = 0.f; }
      if (x0 < 0 || x0 >= WW) { w00 = 0.f; w10 = 0.f; }
      if (x1 < 0 || x1 >= WW) { w01 = 0.f; w11 = 0.f; }
      int y0c = min(max(y0,0),HH-1), y1c = min(max(y1,0),HH-1);
      int x0c = min(max(x0,0),WW-1), x1c = min(max(x1,0),WW-1);
      float g00 = base[(size_t)(y0c*WW + x0c)*CCH + t];
      float g01 = base[(size_t)(y0c*WW + x1c)*CCH + t];
      float g10 = base[(size_t)(y1c*WW + x0c)*CCH + t];
      float g11 = base[(size_t)(y1c*WW + x1c)*CCH + t];
      float v = w00*g00 + w01*g01 + w10*g10 + w11*g11;
      cols[(size_t)(p - p_start)*CK + k*CCH + t] = __float2bfloat16(v);
    }
  }
}

// ---------------- GEMM: C[p][o] += cols[p][kc] * wp[o][kc], bf16 MFMA ----------------
__global__ __launch_bounds__(256) void k_gemm(const __hip_bfloat16* __restrict__ A,
    const __hip_bfloat16* __restrict__ B, float* __restrict__ C, int p_start){
  __shared__ __hip_bfloat16 Alds[128*32];
  __shared__ __hip_bfloat16 Blds[128*32];
  int t = threadIdx.x;
  int lane = t & 63, wid = t >> 6;
  int wr = wid >> 1, wc = wid & 1;
  int row0 = blockIdx.x * 128;
  int col0 = blockIdx.y * 128;
  f32x4 acc[4][4];
#pragma unroll
  for (int i = 0; i < 4; ++i)
#pragma unroll
    for (int j = 0; j < 4; ++j)
      acc[i][j] = (f32x4){0.f,0.f,0.f,0.f};

  int sr = lane >> 2, skq = lane & 3;
  const __hip_bfloat16* aptr0 = A + (size_t)(row0 + (wid*2+0)*16 + sr)*CK + skq*8;
  const __hip_bfloat16* aptr1 = A + (size_t)(row0 + (wid*2+1)*16 + sr)*CK + skq*8;
  const __hip_bfloat16* bptr0 = B + (size_t)(col0 + (wid*2+0)*16 + sr)*CK + skq*8;
  const __hip_bfloat16* bptr1 = B + (size_t)(col0 + (wid*2+1)*16 + sr)*CK + skq*8;
  __hip_bfloat16* lA0 = Alds + (wid*2+0)*512;
  __hip_bfloat16* lA1 = Alds + (wid*2+1)*512;
  __hip_bfloat16* lB0 = Blds + (wid*2+0)*512;
  __hip_bfloat16* lB1 = Blds + (wid*2+1)*512;

  int fr = lane & 15, fk = (lane >> 4) * 8;

  for (int kt = 0; kt < 72; ++kt){
#if __has_builtin(__builtin_amdgcn_global_load_lds)
    __builtin_amdgcn_global_load_lds((const __attribute__((address_space(1))) void*)(aptr0),
                                     (__attribute__((address_space(3))) void*)(lA0), 16, 0, 0);
    __builtin_amdgcn_global_load_lds((const __attribute__((address_space(1))) void*)(aptr1),
                                     (__attribute__((address_space(3))) void*)(lA1), 16, 0, 0);
    __builtin_amdgcn_global_load_lds((const __attribute__((address_space(1))) void*)(bptr0),
                                     (__attribute__((address_space(3))) void*)(lB0), 16, 0, 0);
    __builtin_amdgcn_global_load_lds((const __attribute__((address_space(1))) void*)(bptr1),
                                     (__attribute__((address_space(3))) void*)(lB1), 16, 0, 0);
#else
    *(bf16x8*)&lA0[(lane)*8] = *(const bf16x8*)aptr0;
    *(bf16x8*)&lA1[(lane)*8] = *(const bf16x8*)aptr1;
    *(bf16x8*)&lB0[(lane)*8] = *(const bf16x8*)bptr0;
    *(bf16x8*)&lB1[(lane)*8] = *(const bf16x8*)bptr1;
#endif
    aptr0 += 32; aptr1 += 32; bptr0 += 32; bptr1 += 32;
    __syncthreads();
    bf16x8 av[4], bv[4];
#pragma unroll
    for (int mi = 0; mi < 4; ++mi)
      av[mi] = *(const bf16x8*)&Alds[(wr*64 + mi*16 + fr)*32 + fk];
#pragma unroll
    for (int ni = 0; ni < 4; ++ni)
      bv[ni] = *(const bf16x8*)&Blds[(wc*64 + ni*16 + fr)*32 + fk];
#pragma unroll
    for (int mi = 0; mi < 4; ++mi)
#pragma unroll
      for (int ni = 0; ni < 4; ++ni)
        acc[mi][ni] = __builtin_amdgcn_mfma_f32_16x16x32_bf16(av[mi], bv[ni], acc[mi][ni], 0, 0, 0);
    __syncthreads();
  }
  int prow0 = p_start + row0 + wr*64;
  int ocol0 = col0 + wc*64;
#pragma unroll
  for (int mi = 0; mi < 4; ++mi)
#pragma unroll
    for (int ni = 0; ni < 4; ++ni){
      int rr = prow0 + mi*16 + (lane>>4)*4;
      int cc = ocol0 + ni*16 + (lane&15);
#pragma unroll
      for (int r = 0; r < 4; ++r)
        C[(size_t)(rr + r)*CCH + cc] = acc[mi][ni][r];
    }
}

// ---------------- BN stats: per-channel sum & sumsq ----------------
__global__ __launch_bounds__(256) void k_bn_stats(const float* __restrict__ v,
                                                  float* __restrict__ stats){
  int t = threadIdx.x;
  int p0 = blockIdx.x * 128;
  float s = 0.f, ss = 0.f;
  for (int i = 0; i < 128; ++i){
    float x = v[(size_t)(p0 + i)*CCH + t];
    s += x; ss += x*x;
  }
  atomicAdd(&stats[t], s);
  atomicAdd(&stats[CCH + t], ss);
}

// ---------------- BN apply + ReLU (channels-last in/out) ----------------
__global__ __launch_bounds__(256) void k_bn_apply(const float* __restrict__ v,
    const float* __restrict__ stats, const float* __restrict__ g,
    const float* __restrict__ bb, float* __restrict__ y){
  const float inv = 1.f/16384.f;
  for (size_t i = (size_t)blockIdx.x*256 + threadIdx.x; i < (size_t)NPIX*CCH;
       i += (size_t)gridDim.x*256){
    int c = (int)(i & 255);
    float mean = stats[c]*inv;
    float var  = stats[CCH + c]*inv - mean*mean;
    float sc = g[c]*rsqrtf(var + EPSB);
    float sh = bb[c] - mean*sc;
    float val = fmaf(v[i], sc, sh);
    y[i] = val > 0.f ? val : 0.f;
  }
}

// ---------------- final: BN2 + residual + ReLU, transpose to NCHW ----------------
__global__ __launch_bounds__(256) void k_final(const float* __restrict__ v,
    const float* __restrict__ stats, const float* __restrict__ g,
    const float* __restrict__ bb, const float* __restrict__ x,
    float* __restrict__ out){
  __shared__ float tile[64][65];
  int hw0 = blockIdx.x * 64;
  int o0  = blockIdx.y * 64;
  int n   = blockIdx.z;
  int t = threadIdx.x;
  int col = t & 63, rb = t >> 6;
  const float inv = 1.f/16384.f;
#pragma unroll
  for (int r = 0; r < 16; ++r){
    int pl = rb + r*4;
    tile[pl][col] = v[(size_t)(n*HWSZ + hw0 + pl)*CCH + o0 + col];
  }
  __syncthreads();
#pragma unroll
  for (int r = 0; r < 16; ++r){
    int ol = rb + r*4;
    int o = o0 + ol;
    float mean = stats[o]*inv;
    float var  = stats[CCH + o]*inv - mean*mean;
    float sc = g[o]*rsqrtf(var + EPSB);
    float sh = bb[o] - mean*sc;
    size_t gi = (size_t)(n*CCH + o)*HWSZ + hw0 + col;
    float val = fmaf(tile[col][ol], sc, sh) + x[gi];
    out[gi] = val > 0.f ? val : 0.f;
  }
}

extern "C" void kernel_launch(void* const* d_in, const int* in_sizes, int n_in,
                              void* d_out, int out_size, void* d_ws, size_t ws_size,
                              hipStream_t stream){
  const float* x     = (const float*)d_in[0];
  const float* tm1_w = (const float*)d_in[1];
  const float* tm1_b = (const float*)d_in[2];
  const float* tr1_w = (const float*)d_in[3];
  const float* tr1_b = (const float*)d_in[4];
  const float* dcn1_w= (const float*)d_in[5];
  const float* bn1_g = (const float*)d_in[6];
  const float* bn1_b = (const float*)d_in[7];
  const float* tm2_w = (const float*)d_in[8];
  const float* tm2_b = (const float*)d_in[9];
  const float* tr2_w = (const float*)d_in[10];
  const float* tr2_b = (const float*)d_in[11];
  const float* dcn2_w= (const float*)d_in[12];
  const float* bn2_g = (const float*)d_in[13];
  const float* bn2_b = (const float*)d_in[14];
  float* out = (float*)d_out;

  char* ws = (char*)d_ws;
  size_t cursor = 0;
  auto alloc = [&](size_t bytes)->char*{
    char* p = ws + cursor; cursor += (bytes + 255) & ~(size_t)255; return p;
  };
  float* xT    = (float*)alloc((size_t)NPIX*CCH*4);
  float* ybuf  = (float*)alloc((size_t)NPIX*CCH*4);
  float* gout  = (float*)alloc((size_t)NPIX*CCH*4);
  float* offb  = (float*)alloc((size_t)NPIX*9*2*4);
  float* woff1 = (float*)alloc(CCH*54*4);
  float* woff2 = (float*)alloc(CCH*54*4);
  __hip_bfloat16* wg1 = (__hip_bfloat16*)alloc((size_t)CCH*CK*2);
  __hip_bfloat16* wg2 = (__hip_bfloat16*)alloc((size_t)CCH*CK*2);
  float* stats = (float*)alloc(1024*4);
  size_t avail = ws_size > cursor ? ws_size - cursor : 0;
  size_t maxp = avail / ((size_t)CK*2);
  int pchunk = (int)(maxp > NPIX ? NPIX : maxp);
  pchunk &= ~127;
  if (pchunk < 128) pchunk = 128;
  __hip_bfloat16* cols = (__hip_bfloat16*)alloc((size_t)pchunk*CK*2);

  hipMemsetAsync(stats, 0, 1024*4, stream);
  k_transpose_in<<<dim3(64,4,4),256,0,stream>>>(x, xT);
  k_woff_perm<<<54,256,0,stream>>>(tm1_w, tr1_w, woff1);
  k_woff_perm<<<54,256,0,stream>>>(tm2_w, tr2_w, woff2);
  k_wgemm_perm<<<2304,256,0,stream>>>(dcn1_w, wg1);
  k_wgemm_perm<<<2304,256,0,stream>>>(dcn2_w, wg2);

  // ---- layer 1 ----
  k_offsets<<<2048,256,0,stream>>>(xT, woff1, tm1_b, tr1_b, offb);
  for (int p0 = 0; p0 < NPIX; p0 += pchunk){
    int pc = (NPIX - p0 < pchunk) ? (NPIX - p0) : pchunk;
    k_im2col<<<pc/4,256,0,stream>>>(xT, offb, cols, p0, pc);
    k_gemm<<<dim3(pc/128,2),256,0,stream>>>(cols, wg1, gout, p0);
  }
  k_bn_stats<<<128,256,0,stream>>>(gout, stats);
  k_bn_apply<<<2048,256,0,stream>>>(gout, stats, bn1_g, bn1_b, ybuf);

  // ---- layer 2 ----
  k_offsets<<<2048,256,0,stream>>>(ybuf, woff2, tm2_b, tr2_b, offb);
  for (int p0 = 0; p0 < NPIX; p0 += pchunk){
    int pc = (NPIX - p0 < pchunk) ? (NPIX - p0) : pchunk;
    k_im2col<<<pc/4,256,0,stream>>>(ybuf, offb, cols, p0, pc);
    k_gemm<<<dim3(pc/128,2),256,0,stream>>>(cols, wg2, gout, p0);
  }
  k_bn_stats<<<128,256,0,stream>>>(gout, stats + 512);
  k_final<<<dim3(64,4,4),256,0,stream>>>(gout, stats + 512, bn2_g, bn2_b, x, out);
}

// Round 2
// 270.523 us; speedup vs baseline: 1.4463x; 1.4463x over previous
//
#include <hip/hip_runtime.h>
#include <hip/hip_bf16.h>

#define HH 64
#define WW 64
#define HWSZ 4096
#define NBATCH 4
#define CCH 256
#define NPIX 16384   // NBATCH*HWSZ
#define CK 2304      // 9*256
#define EPSB 1e-5f

typedef __attribute__((ext_vector_type(8))) short bf16x8;
typedef __attribute__((ext_vector_type(4))) float f32x4;

// ---------------- transpose x (N,C,H,W) -> xT (N,HW,C) ----------------
__global__ __launch_bounds__(256) void k_transpose_in(const float* __restrict__ x,
                                                      float* __restrict__ xT){
  __shared__ float tile[64][65];
  int hw0 = blockIdx.x * 64;
  int c0  = blockIdx.y * 64;
  int n   = blockIdx.z;
  int t = threadIdx.x;
  int col = t & 63, rb = t >> 6;
#pragma unroll
  for (int r = 0; r < 16; ++r){
    int cl = rb + r*4;
    tile[cl][col] = x[(size_t)(n*CCH + c0 + cl)*HWSZ + hw0 + col];
  }
  __syncthreads();
#pragma unroll
  for (int r = 0; r < 16; ++r){
    int hwl = rb + r*4;
    xT[(size_t)(n*HWSZ + hw0 + hwl)*CCH + c0 + col] = tile[col][hwl];
  }
}

// ---------------- permute offset-conv weights to [k][j][c] (c contiguous) ----------------
__global__ void k_woff_perm(const float* __restrict__ tmw, const float* __restrict__ trw,
                            float* __restrict__ woff){
  int idx = blockIdx.x*256 + threadIdx.x;   // 9*6*256 = 13824
  if (idx >= 9*6*CCH) return;
  int k = idx / (6*CCH); int rem = idx % (6*CCH); int j = rem >> 8; int c = rem & 255;
  float v = (j < 4) ? tmw[(size_t)(j*CCH + c)*9 + k]
                    : trw[(size_t)((j-4)*CCH + c)*9 + k];
  woff[idx] = v;
}

// ---------------- permute dcn weights (Co,C,9) -> bf16 [o][k*256+c] ----------------
__global__ void k_wgemm_perm(const float* __restrict__ w, __hip_bfloat16* __restrict__ wp){
  int idx = blockIdx.x*256 + threadIdx.x;    // 589824 total
  if (idx >= CCH*CK) return;
  int o = idx / CK; int rem = idx % CK; int k = rem >> 8; int c = rem & 255;
  wp[idx] = __float2bfloat16(w[(size_t)(o*CCH + c)*9 + k]);
}

// ---------------- offset generation: conv3x3(6ch) + make_offset, no LDS ----------------
// 1 wave = 8 consecutive pixels (same row). lane = 4 channels. Weights [k][j][c]
// read as wave-wide float4 (L1 broadcast line), reused across the 8 pixels.
__global__ __launch_bounds__(256) void k_offsets(const float* __restrict__ src,
    const float* __restrict__ wofft, const float* __restrict__ tmb,
    const float* __restrict__ trb, float* __restrict__ off){
  int t = threadIdx.x;
  int wid = t >> 6, lane = t & 63;
  int pbase = blockIdx.x*32 + wid*8;          // 512 blocks * 4 waves * 8 pixels
  int n = pbase >> 12; int hw = pbase & 4095; int h = hw >> 6; int w0 = hw & 63;
  const float* base = src + (size_t)n*HWSZ*CCH + lane*4;

  float acc[8][6];
#pragma unroll
  for (int pi = 0; pi < 8; ++pi)
#pragma unroll
    for (int j = 0; j < 6; ++j) acc[pi][j] = 0.f;

  for (int k = 0; k < 9; ++k){
    int ky = k/3 - 1, kx = k%3 - 1;
    int yy = h + ky;
    if (yy < 0 || yy >= HH) continue;
    float4 wv[6];
#pragma unroll
    for (int j = 0; j < 6; ++j)
      wv[j] = *(const float4*)(wofft + ((k*6 + j) << 8) + lane*4);
#pragma unroll
    for (int pi = 0; pi < 8; ++pi){
      int xx = w0 + pi + kx;
      if (xx < 0 || xx >= WW) continue;
      float4 s4 = *(const float4*)(base + (size_t)(yy*WW + xx)*CCH);
#pragma unroll
      for (int j = 0; j < 6; ++j)
        acc[pi][j] += s4.x*wv[j].x + s4.y*wv[j].y + s4.z*wv[j].z + s4.w*wv[j].w;
    }
  }

  // butterfly reduce across the 64 lanes (all lanes end with the sum)
#pragma unroll
  for (int pi = 0; pi < 8; ++pi)
#pragma unroll
    for (int j = 0; j < 6; ++j){
      float v = acc[pi][j];
#pragma unroll
      for (int m = 32; m >= 1; m >>= 1) v += __shfl_xor(v, m);
      acc[pi][j] = v;
    }

  float b0 = tmb[0], b1 = tmb[1], b2 = tmb[2], b3 = tmb[3];
  float c0 = trb[0], c1 = trb[1];
  if (lane < 18){
    int k = lane >> 1, comp = lane & 1;
    float dy = (float)(k/3 - 1), dx = (float)(k%3 - 1);
#pragma unroll
    for (int pi = 0; pi < 8; ++pi){
      int p = pbase + pi;
      float val;
      if (comp == 0)
        val = (acc[pi][0] + b0)*dy + (acc[pi][1] + b1)*dx - dy + acc[pi][4] + c0;
      else
        val = (acc[pi][2] + b2)*dy + (acc[pi][3] + b3)*dx - dx + acc[pi][5] + c1;
      off[((size_t)p*9 + k)*2 + comp] = val;
    }
  }
}

// ---------------- im2col with bilinear sampling -> bf16 cols [p][k*256+c] ----------------
__global__ __launch_bounds__(256) void k_im2col(const float* __restrict__ src,
    const float* __restrict__ off, __hip_bfloat16* __restrict__ cols,
    int p_start, int p_count){
  int t = threadIdx.x;
  int pb = p_start + blockIdx.x*4;
#pragma unroll
  for (int pi = 0; pi < 4; ++pi){
    int p = pb + pi;
    int n = p >> 12; int hw = p & 4095; int h = hw >> 6; int w = hw & 63;
    const float* base = src + (size_t)n*HWSZ*CCH;
#pragma unroll
    for (int k = 0; k < 9; ++k){
      float offy = off[((size_t)p*9 + k)*2 + 0];
      float offx = off[((size_t)p*9 + k)*2 + 1];
      float py = (float)(h + k/3 - 1) + offy;
      float px = (float)(w + k%3 - 1) + offx;
      float y0f = floorf(py), x0f = floorf(px);
      float wy = py - y0f, wx = px - x0f;
      int y0 = (int)y0f, x0 = (int)x0f;
      int y1 = y0 + 1, x1 = x0 + 1;
      float w00 = (1.f-wy)*(1.f-wx), w01 = (1.f-wy)*wx;
      float w10 = wy*(1.f-wx),       w11 = wy*wx;
      if (y0 < 0 || y0 >= HH) { w00 = 0.f; w01 = 0.f; }
      if (y1 < 0 || y1 >= HH) { w10 = 0.f; w11 = 0.f; }
      if (x0 < 0 || x0 >= WW) { w00 = 0.f; w10 = 0.f; }
      if (x1 < 0 || x1 >= WW) { w01 = 0.f; w11 = 0.f; }
      int y0c = min(max(y0,0),HH-1), y1c = min(max(y1,0),HH-1);
      int x0c = min(max(x0,0),WW-1), x1c = min(max(x1,0),WW-1);
      float g00 = base[(size_t)(y0c*WW + x0c)*CCH + t];
      float g01 = base[(size_t)(y0c*WW + x1c)*CCH + t];
      float g10 = base[(size_t)(y1c*WW + x0c)*CCH + t];
      float g11 = base[(size_t)(y1c*WW + x1c)*CCH + t];
      float v = w00*g00 + w01*g01 + w10*g10 + w11*g11;
      cols[(size_t)(p - p_start)*CK + k*CCH + t] = __float2bfloat16(v);
    }
  }
}

// ---------------- GEMM: C[p][o] += cols[p][kc] * wp[o][kc], bf16 MFMA ----------------
__global__ __launch_bounds__(256) void k_gemm(const __hip_bfloat16* __restrict__ A,
    const __hip_bfloat16* __restrict__ B, float* __restrict__ C, int p_start){
  __shared__ __hip_bfloat16 Alds[128*32];
  __shared__ __hip_bfloat16 Blds[128*32];
  int t = threadIdx.x;
  int lane = t & 63, wid = t >> 6;
  int wr = wid >> 1, wc = wid & 1;
  int row0 = blockIdx.x * 128;
  int col0 = blockIdx.y * 128;
  f32x4 acc[4][4];
#pragma unroll
  for (int i = 0; i < 4; ++i)
#pragma unroll
    for (int j = 0; j < 4; ++j)
      acc[i][j] = (f32x4){0.f,0.f,0.f,0.f};

  int sr = lane >> 2, skq = lane & 3;
  const __hip_bfloat16* aptr0 = A + (size_t)(row0 + (wid*2+0)*16 + sr)*CK + skq*8;
  const __hip_bfloat16* aptr1 = A + (size_t)(row0 + (wid*2+1)*16 + sr)*CK + skq*8;
  const __hip_bfloat16* bptr0 = B + (size_t)(col0 + (wid*2+0)*16 + sr)*CK + skq*8;
  const __hip_bfloat16* bptr1 = B + (size_t)(col0 + (wid*2+1)*16 + sr)*CK + skq*8;
  __hip_bfloat16* lA0 = Alds + (wid*2+0)*512;
  __hip_bfloat16* lA1 = Alds + (wid*2+1)*512;
  __hip_bfloat16* lB0 = Blds + (wid*2+0)*512;
  __hip_bfloat16* lB1 = Blds + (wid*2+1)*512;

  int fr = lane & 15, fk = (lane >> 4) * 8;

  for (int kt = 0; kt < 72; ++kt){
#if __has_builtin(__builtin_amdgcn_global_load_lds)
    __builtin_amdgcn_global_load_lds((const __attribute__((address_space(1))) void*)(aptr0),
                                     (__attribute__((address_space(3))) void*)(lA0), 16, 0, 0);
    __builtin_amdgcn_global_load_lds((const __attribute__((address_space(1))) void*)(aptr1),
                                     (__attribute__((address_space(3))) void*)(lA1), 16, 0, 0);
    __builtin_amdgcn_global_load_lds((const __attribute__((address_space(1))) void*)(bptr0),
                                     (__attribute__((address_space(3))) void*)(lB0), 16, 0, 0);
    __builtin_amdgcn_global_load_lds((const __attribute__((address_space(1))) void*)(bptr1),
                                     (__attribute__((address_space(3))) void*)(lB1), 16, 0, 0);
#else
    *(bf16x8*)&lA0[(lane)*8] = *(const bf16x8*)aptr0;
    *(bf16x8*)&lA1[(lane)*8] = *(const bf16x8*)aptr1;
    *(bf16x8*)&lB0[(lane)*8] = *(const bf16x8*)bptr0;
    *(bf16x8*)&lB1[(lane)*8] = *(const bf16x8*)bptr1;
#endif
    aptr0 += 32; aptr1 += 32; bptr0 += 32; bptr1 += 32;
    __syncthreads();
    bf16x8 av[4], bv[4];
#pragma unroll
    for (int mi = 0; mi < 4; ++mi)
      av[mi] = *(const bf16x8*)&Alds[(wr*64 + mi*16 + fr)*32 + fk];
#pragma unroll
    for (int ni = 0; ni < 4; ++ni)
      bv[ni] = *(const bf16x8*)&Blds[(wc*64 + ni*16 + fr)*32 + fk];
#pragma unroll
    for (int mi = 0; mi < 4; ++mi)
#pragma unroll
      for (int ni = 0; ni < 4; ++ni)
        acc[mi][ni] = __builtin_amdgcn_mfma_f32_16x16x32_bf16(av[mi], bv[ni], acc[mi][ni], 0, 0, 0);
    __syncthreads();
  }
  int prow0 = p_start + row0 + wr*64;
  int ocol0 = col0 + wc*64;
#pragma unroll
  for (int mi = 0; mi < 4; ++mi)
#pragma unroll
    for (int ni = 0; ni < 4; ++ni){
      int rr = prow0 + mi*16 + (lane>>4)*4;
      int cc = ocol0 + ni*16 + (lane&15);
#pragma unroll
      for (int r = 0; r < 4; ++r)
        C[(size_t)(rr + r)*CCH + cc] = acc[mi][ni][r];
    }
}

// ---------------- BN stats: per-channel sum & sumsq ----------------
__global__ __launch_bounds__(256) void k_bn_stats(const float* __restrict__ v,
                                                  float* __restrict__ stats){
  int t = threadIdx.x;
  int p0 = blockIdx.x * 128;
  float s = 0.f, ss = 0.f;
  for (int i = 0; i < 128; ++i){
    float x = v[(size_t)(p0 + i)*CCH + t];
    s += x; ss += x*x;
  }
  atomicAdd(&stats[t], s);
  atomicAdd(&stats[CCH + t], ss);
}

// ---------------- BN apply + ReLU (channels-last in/out) ----------------
__global__ __launch_bounds__(256) void k_bn_apply(const float* __restrict__ v,
    const float* __restrict__ stats, const float* __restrict__ g,
    const float* __restrict__ bb, float* __restrict__ y){
  const float inv = 1.f/16384.f;
  for (size_t i = (size_t)blockIdx.x*256 + threadIdx.x; i < (size_t)NPIX*CCH;
       i += (size_t)gridDim.x*256){
    int c = (int)(i & 255);
    float mean = stats[c]*inv;
    float var  = stats[CCH + c]*inv - mean*mean;
    float sc = g[c]*rsqrtf(var + EPSB);
    float sh = bb[c] - mean*sc;
    float val = fmaf(v[i], sc, sh);
    y[i] = val > 0.f ? val : 0.f;
  }
}

// ---------------- final: BN2 + residual + ReLU, transpose to NCHW ----------------
__global__ __launch_bounds__(256) void k_final(const float* __restrict__ v,
    const float* __restrict__ stats, const float* __restrict__ g,
    const float* __restrict__ bb, const float* __restrict__ x,
    float* __restrict__ out){
  __shared__ float tile[64][65];
  int hw0 = blockIdx.x * 64;
  int o0  = blockIdx.y * 64;
  int n   = blockIdx.z;
  int t = threadIdx.x;
  int col = t & 63, rb = t >> 6;
  const float inv = 1.f/16384.f;
#pragma unroll
  for (int r = 0; r < 16; ++r){
    int pl = rb + r*4;
    tile[pl][col] = v[(size_t)(n*HWSZ + hw0 + pl)*CCH + o0 + col];
  }
  __syncthreads();
#pragma unroll
  for (int r = 0; r < 16; ++r){
    int ol = rb + r*4;
    int o = o0 + ol;
    float mean = stats[o]*inv;
    float var  = stats[CCH + o]*inv - mean*mean;
    float sc = g[o]*rsqrtf(var + EPSB);
    float sh = bb[o] - mean*sc;
    size_t gi = (size_t)(n*CCH + o)*HWSZ + hw0 + col;
    float val = fmaf(tile[col][ol], sc, sh) + x[gi];
    out[gi] = val > 0.f ? val : 0.f;
  }
}

extern "C" void kernel_launch(void* const* d_in, const int* in_sizes, int n_in,
                              void* d_out, int out_size, void* d_ws, size_t ws_size,
                              hipStream_t stream){
  const float* x     = (const float*)d_in[0];
  const float* tm1_w = (const float*)d_in[1];
  const float* tm1_b = (const float*)d_in[2];
  const float* tr1_w = (const float*)d_in[3];
  const float* tr1_b = (const float*)d_in[4];
  const float* dcn1_w= (const float*)d_in[5];
  const float* bn1_g = (const float*)d_in[6];
  const float* bn1_b = (const float*)d_in[7];
  const float* tm2_w = (const float*)d_in[8];
  const float* tm2_b = (const float*)d_in[9];
  const float* tr2_w = (const float*)d_in[10];
  const float* tr2_b = (const float*)d_in[11];
  const float* dcn2_w= (const float*)d_in[12];
  const float* bn2_g = (const float*)d_in[13];
  const float* bn2_b = (const float*)d_in[14];
  float* out = (float*)d_out;

  char* ws = (char*)d_ws;
  size_t cursor = 0;
  auto alloc = [&](size_t bytes)->char*{
    char* p = ws + cursor; cursor += (bytes + 255) & ~(size_t)255; return p;
  };
  float* xT    = (float*)alloc((size_t)NPIX*CCH*4);
  float* ybuf  = (float*)alloc((size_t)NPIX*CCH*4);
  float* gout  = (float*)alloc((size_t)NPIX*CCH*4);
  float* offb  = (float*)alloc((size_t)NPIX*9*2*4);
  float* woff1 = (float*)alloc(9*6*CCH*4);
  float* woff2 = (float*)alloc(9*6*CCH*4);
  __hip_bfloat16* wg1 = (__hip_bfloat16*)alloc((size_t)CCH*CK*2);
  __hip_bfloat16* wg2 = (__hip_bfloat16*)alloc((size_t)CCH*CK*2);
  float* stats = (float*)alloc(1024*4);
  size_t avail = ws_size > cursor ? ws_size - cursor : 0;
  size_t maxp = avail / ((size_t)CK*2);
  int pchunk = (int)(maxp > NPIX ? NPIX : maxp);
  pchunk &= ~127;
  if (pchunk < 128) pchunk = 128;
  __hip_bfloat16* cols = (__hip_bfloat16*)alloc((size_t)pchunk*CK*2);

  hipMemsetAsync(stats, 0, 1024*4, stream);
  k_transpose_in<<<dim3(64,4,4),256,0,stream>>>(x, xT);
  k_woff_perm<<<54,256,0,stream>>>(tm1_w, tr1_w, woff1);
  k_woff_perm<<<54,256,0,stream>>>(tm2_w, tr2_w, woff2);
  k_wgemm_perm<<<2304,256,0,stream>>>(dcn1_w, wg1);
  k_wgemm_perm<<<2304,256,0,stream>>>(dcn2_w, wg2);

  // ---- layer 1 ----
  k_offsets<<<512,256,0,stream>>>(xT, woff1, tm1_b, tr1_b, offb);
  for (int p0 = 0; p0 < NPIX; p0 += pchunk){
    int pc = (NPIX - p0 < pchunk) ? (NPIX - p0) : pchunk;
    k_im2col<<<pc/4,256,0,stream>>>(xT, offb, cols, p0, pc);
    k_gemm<<<dim3(pc/128,2),256,0,stream>>>(cols, wg1, gout, p0);
  }
  k_bn_stats<<<128,256,0,stream>>>(gout, stats);
  k_bn_apply<<<2048,256,0,stream>>>(gout, stats, bn1_g, bn1_b, ybuf);

  // ---- layer 2 ----
  k_offsets<<<512,256,0,stream>>>(ybuf, woff2, tm2_b, tr2_b, offb);
  for (int p0 = 0; p0 < NPIX; p0 += pchunk){
    int pc = (NPIX - p0 < pchunk) ? (NPIX - p0) : pchunk;
    k_im2col<<<pc/4,256,0,stream>>>(ybuf, offb, cols, p0, pc);
    k_gemm<<<dim3(pc/128,2),256,0,stream>>>(cols, wg2, gout, p0);
  }
  k_bn_stats<<<128,256,0,stream>>>(gout, stats + 512);
  k_final<<<dim3(64,4,4),256,0,stream>>>(gout, stats + 512, bn2_g, bn2_b, x, out);
}

// Round 3
// 251.632 us; speedup vs baseline: 1.5549x; 1.0751x over previous
//
#include <hip/hip_runtime.h>
#include <hip/hip_bf16.h>

#define HH 64
#define WW 64
#define HWSZ 4096
#define NBATCH 4
#define CCH 256
#define NPIX 16384   // NBATCH*HWSZ
#define CK 2304      // 9*256
#define EPSB 1e-5f

typedef __attribute__((ext_vector_type(8))) short bf16x8;
typedef __attribute__((ext_vector_type(4))) float f32x4;

static __device__ __forceinline__ unsigned short f2bf(float f){
  __hip_bfloat16 h = __float2bfloat16(f);
  return *(unsigned short*)&h;
}

// ---------------- transpose x (N,C,H,W) -> xT (N,HW,C) ----------------
__global__ __launch_bounds__(256) void k_transpose_in(const float* __restrict__ x,
                                                      float* __restrict__ xT){
  __shared__ float tile[64][65];
  int hw0 = blockIdx.x * 64;
  int c0  = blockIdx.y * 64;
  int n   = blockIdx.z;
  int t = threadIdx.x;
  int col = t & 63, rb = t >> 6;
#pragma unroll
  for (int r = 0; r < 16; ++r){
    int cl = rb + r*4;
    tile[cl][col] = x[(size_t)(n*CCH + c0 + cl)*HWSZ + hw0 + col];
  }
  __syncthreads();
#pragma unroll
  for (int r = 0; r < 16; ++r){
    int hwl = rb + r*4;
    xT[(size_t)(n*HWSZ + hw0 + hwl)*CCH + c0 + col] = tile[col][hwl];
  }
}

// ---------------- permute offset-conv weights to [k][j][c] (c contiguous) ----------------
__global__ void k_woff_perm(const float* __restrict__ tmw, const float* __restrict__ trw,
                            float* __restrict__ woff){
  int idx = blockIdx.x*256 + threadIdx.x;   // 9*6*256 = 13824
  if (idx >= 9*6*CCH) return;
  int k = idx / (6*CCH); int rem = idx % (6*CCH); int j = rem >> 8; int c = rem & 255;
  float v = (j < 4) ? tmw[(size_t)(j*CCH + c)*9 + k]
                    : trw[(size_t)((j-4)*CCH + c)*9 + k];
  woff[idx] = v;
}

// ---------------- permute dcn weights (Co,C,9) -> bf16 [o][k*256+c] ----------------
__global__ void k_wgemm_perm(const float* __restrict__ w, __hip_bfloat16* __restrict__ wp){
  int idx = blockIdx.x*256 + threadIdx.x;    // 589824 total
  if (idx >= CCH*CK) return;
  int o = idx / CK; int rem = idx % CK; int k = rem >> 8; int c = rem & 255;
  wp[idx] = __float2bfloat16(w[(size_t)(o*CCH + c)*9 + k]);
}

// ---------------- offset generation: conv3x3(6ch) + make_offset, no LDS ----------------
__global__ __launch_bounds__(256) void k_offsets(const float* __restrict__ src,
    const float* __restrict__ wofft, const float* __restrict__ tmb,
    const float* __restrict__ trb, float* __restrict__ off){
  int t = threadIdx.x;
  int wid = t >> 6, lane = t & 63;
  int pbase = blockIdx.x*32 + wid*8;          // 512 blocks * 4 waves * 8 pixels
  int n = pbase >> 12; int hw = pbase & 4095; int h = hw >> 6; int w0 = hw & 63;
  const float* base = src + (size_t)n*HWSZ*CCH + lane*4;

  float acc[8][6];
#pragma unroll
  for (int pi = 0; pi < 8; ++pi)
#pragma unroll
    for (int j = 0; j < 6; ++j) acc[pi][j] = 0.f;

  for (int k = 0; k < 9; ++k){
    int ky = k/3 - 1, kx = k%3 - 1;
    int yy = h + ky;
    if (yy < 0 || yy >= HH) continue;
    float4 wv[6];
#pragma unroll
    for (int j = 0; j < 6; ++j)
      wv[j] = *(const float4*)(wofft + ((k*6 + j) << 8) + lane*4);
#pragma unroll
    for (int pi = 0; pi < 8; ++pi){
      int xx = w0 + pi + kx;
      if (xx < 0 || xx >= WW) continue;
      float4 s4 = *(const float4*)(base + (size_t)(yy*WW + xx)*CCH);
#pragma unroll
      for (int j = 0; j < 6; ++j)
        acc[pi][j] += s4.x*wv[j].x + s4.y*wv[j].y + s4.z*wv[j].z + s4.w*wv[j].w;
    }
  }

#pragma unroll
  for (int pi = 0; pi < 8; ++pi)
#pragma unroll
    for (int j = 0; j < 6; ++j){
      float v = acc[pi][j];
#pragma unroll
      for (int m = 32; m >= 1; m >>= 1) v += __shfl_xor(v, m);
      acc[pi][j] = v;
    }

  float b0 = tmb[0], b1 = tmb[1], b2 = tmb[2], b3 = tmb[3];
  float c0 = trb[0], c1 = trb[1];
  if (lane < 18){
    int k = lane >> 1, comp = lane & 1;
    float dy = (float)(k/3 - 1), dx = (float)(k%3 - 1);
#pragma unroll
    for (int pi = 0; pi < 8; ++pi){
      int p = pbase + pi;
      float val;
      if (comp == 0)
        val = (acc[pi][0] + b0)*dy + (acc[pi][1] + b1)*dx - dy + acc[pi][4] + c0;
      else
        val = (acc[pi][2] + b2)*dy + (acc[pi][3] + b3)*dx - dx + acc[pi][5] + c1;
      off[((size_t)p*9 + k)*2 + comp] = val;
    }
  }
}

// ---------------- im2col v2: 2-phase (uniform setup once -> LDS table; wave gather) ----------------
// Block = 32 pixels, 512 threads (8 waves). Phase 1: 288 (px,tap) pairs -> 4 corner byte
// offsets + 4 masked weights in LDS. Phase 2: wave w handles slots w, w+8, ...; all 64
// lanes broadcast-read the table entry, gather float4 (4ch/lane, 1KB/corner coalesced),
// bilinear fma, pack 4 bf16, 8B store.
__global__ __launch_bounds__(512) void k_im2col(const float* __restrict__ src,
    const float* __restrict__ off, __hip_bfloat16* __restrict__ cols, int p_start){
  __shared__ __align__(16) int   t_off[288][4];
  __shared__ __align__(16) float t_w[288][4];
  int t = threadIdx.x;
  int pbase = p_start + blockIdx.x*32;

  if (t < 288){
    int slot = t;
    int pl = slot / 9; int k = slot - pl*9;
    int p = pbase + pl;
    int n = p >> 12; int hw = p & 4095; int h = hw >> 6; int w = hw & 63;
    float2 of = *(const float2*)(off + ((size_t)p*9 + k)*2);
    float py = (float)(h + k/3 - 1) + of.x;
    float px = (float)(w + (k - (k/3)*3) - 1) + of.y;
    float y0f = floorf(py), x0f = floorf(px);
    float wy = py - y0f, wx = px - x0f;
    int y0 = (int)y0f, x0 = (int)x0f;
    int y1 = y0 + 1, x1 = x0 + 1;
    float w00 = (1.f-wy)*(1.f-wx), w01 = (1.f-wy)*wx;
    float w10 = wy*(1.f-wx),       w11 = wy*wx;
    if (y0 < 0 || y0 >= HH) { w00 = 0.f; w01 = 0.f; }
    if (y1 < 0 || y1 >= HH) { w10 = 0.f; w11 = 0.f; }
    if (x0 < 0 || x0 >= WW) { w00 = 0.f; w10 = 0.f; }
    if (x1 < 0 || x1 >= WW) { w01 = 0.f; w11 = 0.f; }
    int y0c = min(max(y0,0),HH-1), y1c = min(max(y1,0),HH-1);
    int x0c = min(max(x0,0),WW-1), x1c = min(max(x1,0),WW-1);
    int pbix = n << 12;
    t_off[slot][0] = (pbix + y0c*WW + x0c) << 10;   // byte offset, 256ch*4B per pixel
    t_off[slot][1] = (pbix + y0c*WW + x1c) << 10;
    t_off[slot][2] = (pbix + y1c*WW + x0c) << 10;
    t_off[slot][3] = (pbix + y1c*WW + x1c) << 10;
    t_w[slot][0] = w00; t_w[slot][1] = w01; t_w[slot][2] = w10; t_w[slot][3] = w11;
  }
  __syncthreads();

  int wid = t >> 6, lane = t & 63;
  int cb = lane << 4;                       // this lane's 4-channel byte offset
  const char* sbase = (const char*)src;
  __hip_bfloat16* dbase = cols + (size_t)(pbase - p_start)*CK + (lane << 2);

  for (int slot = wid; slot < 288; slot += 8){
    int4   o  = *(const int4*)t_off[slot];
    float4 wv = *(const float4*)t_w[slot];
    float4 g00 = *(const float4*)(sbase + (size_t)(unsigned)(o.x + cb));
    float4 g01 = *(const float4*)(sbase + (size_t)(unsigned)(o.y + cb));
    float4 g10 = *(const float4*)(sbase + (size_t)(unsigned)(o.z + cb));
    float4 g11 = *(const float4*)(sbase + (size_t)(unsigned)(o.w + cb));
    float v0 = wv.x*g00.x + wv.y*g01.x + wv.z*g10.x + wv.w*g11.x;
    float v1 = wv.x*g00.y + wv.y*g01.y + wv.z*g10.y + wv.w*g11.y;
    float v2 = wv.x*g00.z + wv.y*g01.z + wv.z*g10.z + wv.w*g11.z;
    float v3 = wv.x*g00.w + wv.y*g01.w + wv.z*g10.w + wv.w*g11.w;
    int pl = slot / 9; int k = slot - pl*9;
    ushort4 st;
    st.x = f2bf(v0); st.y = f2bf(v1); st.z = f2bf(v2); st.w = f2bf(v3);
    *(ushort4*)(dbase + (size_t)pl*CK + (k << 8)) = st;
  }
}

// ---------------- GEMM: C[p][o] += cols[p][kc] * wp[o][kc], bf16 MFMA ----------------
__global__ __launch_bounds__(256) void k_gemm(const __hip_bfloat16* __restrict__ A,
    const __hip_bfloat16* __restrict__ B, float* __restrict__ C, int p_start){
  __shared__ __hip_bfloat16 Alds[128*32];
  __shared__ __hip_bfloat16 Blds[128*32];
  int t = threadIdx.x;
  int lane = t & 63, wid = t >> 6;
  int wr = wid >> 1, wc = wid & 1;
  int row0 = blockIdx.x * 128;
  int col0 = blockIdx.y * 128;
  f32x4 acc[4][4];
#pragma unroll
  for (int i = 0; i < 4; ++i)
#pragma unroll
    for (int j = 0; j < 4; ++j)
      acc[i][j] = (f32x4){0.f,0.f,0.f,0.f};

  int sr = lane >> 2, skq = lane & 3;
  const __hip_bfloat16* aptr0 = A + (size_t)(row0 + (wid*2+0)*16 + sr)*CK + skq*8;
  const __hip_bfloat16* aptr1 = A + (size_t)(row0 + (wid*2+1)*16 + sr)*CK + skq*8;
  const __hip_bfloat16* bptr0 = B + (size_t)(col0 + (wid*2+0)*16 + sr)*CK + skq*8;
  const __hip_bfloat16* bptr1 = B + (size_t)(col0 + (wid*2+1)*16 + sr)*CK + skq*8;
  __hip_bfloat16* lA0 = Alds + (wid*2+0)*512;
  __hip_bfloat16* lA1 = Alds + (wid*2+1)*512;
  __hip_bfloat16* lB0 = Blds + (wid*2+0)*512;
  __hip_bfloat16* lB1 = Blds + (wid*2+1)*512;

  int fr = lane & 15, fk = (lane >> 4) * 8;

  for (int kt = 0; kt < 72; ++kt){
#if __has_builtin(__builtin_amdgcn_global_load_lds)
    __builtin_amdgcn_global_load_lds((const __attribute__((address_space(1))) void*)(aptr0),
                                     (__attribute__((address_space(3))) void*)(lA0), 16, 0, 0);
    __builtin_amdgcn_global_load_lds((const __attribute__((address_space(1))) void*)(aptr1),
                                     (__attribute__((address_space(3))) void*)(lA1), 16, 0, 0);
    __builtin_amdgcn_global_load_lds((const __attribute__((address_space(1))) void*)(bptr0),
                                     (__attribute__((address_space(3))) void*)(lB0), 16, 0, 0);
    __builtin_amdgcn_global_load_lds((const __attribute__((address_space(1))) void*)(bptr1),
                                     (__attribute__((address_space(3))) void*)(lB1), 16, 0, 0);
#else
    *(bf16x8*)&lA0[(lane)*8] = *(const bf16x8*)aptr0;
    *(bf16x8*)&lA1[(lane)*8] = *(const bf16x8*)aptr1;
    *(bf16x8*)&lB0[(lane)*8] = *(const bf16x8*)bptr0;
    *(bf16x8*)&lB1[(lane)*8] = *(const bf16x8*)bptr1;
#endif
    aptr0 += 32; aptr1 += 32; bptr0 += 32; bptr1 += 32;
    __syncthreads();
    bf16x8 av[4], bv[4];
#pragma unroll
    for (int mi = 0; mi < 4; ++mi)
      av[mi] = *(const bf16x8*)&Alds[(wr*64 + mi*16 + fr)*32 + fk];
#pragma unroll
    for (int ni = 0; ni < 4; ++ni)
      bv[ni] = *(const bf16x8*)&Blds[(wc*64 + ni*16 + fr)*32 + fk];
#pragma unroll
    for (int mi = 0; mi < 4; ++mi)
#pragma unroll
      for (int ni = 0; ni < 4; ++ni)
        acc[mi][ni] = __builtin_amdgcn_mfma_f32_16x16x32_bf16(av[mi], bv[ni], acc[mi][ni], 0, 0, 0);
    __syncthreads();
  }
  int prow0 = p_start + row0 + wr*64;
  int ocol0 = col0 + wc*64;
#pragma unroll
  for (int mi = 0; mi < 4; ++mi)
#pragma unroll
    for (int ni = 0; ni < 4; ++ni){
      int rr = prow0 + mi*16 + (lane>>4)*4;
      int cc = ocol0 + ni*16 + (lane&15);
#pragma unroll
      for (int r = 0; r < 4; ++r)
        C[(size_t)(rr + r)*CCH + cc] = acc[mi][ni][r];
    }
}

// ---------------- BN stats: per-channel sum & sumsq ----------------
__global__ __launch_bounds__(256) void k_bn_stats(const float* __restrict__ v,
                                                  float* __restrict__ stats){
  int t = threadIdx.x;
  int p0 = blockIdx.x * 128;
  float s = 0.f, ss = 0.f;
  for (int i = 0; i < 128; ++i){
    float x = v[(size_t)(p0 + i)*CCH + t];
    s += x; ss += x*x;
  }
  atomicAdd(&stats[t], s);
  atomicAdd(&stats[CCH + t], ss);
}

// ---------------- BN apply + ReLU (channels-last in/out) ----------------
__global__ __launch_bounds__(256) void k_bn_apply(const float* __restrict__ v,
    const float* __restrict__ stats, const float* __restrict__ g,
    const float* __restrict__ bb, float* __restrict__ y){
  const float inv = 1.f/16384.f;
  for (size_t i = (size_t)blockIdx.x*256 + threadIdx.x; i < (size_t)NPIX*CCH;
       i += (size_t)gridDim.x*256){
    int c = (int)(i & 255);
    float mean = stats[c]*inv;
    float var  = stats[CCH + c]*inv - mean*mean;
    float sc = g[c]*rsqrtf(var + EPSB);
    float sh = bb[c] - mean*sc;
    float val = fmaf(v[i], sc, sh);
    y[i] = val > 0.f ? val : 0.f;
  }
}

// ---------------- final: BN2 + residual + ReLU, transpose to NCHW ----------------
__global__ __launch_bounds__(256) void k_final(const float* __restrict__ v,
    const float* __restrict__ stats, const float* __restrict__ g,
    const float* __restrict__ bb, const float* __restrict__ x,
    float* __restrict__ out){
  __shared__ float tile[64][65];
  int hw0 = blockIdx.x * 64;
  int o0  = blockIdx.y * 64;
  int n   = blockIdx.z;
  int t = threadIdx.x;
  int col = t & 63, rb = t >> 6;
  const float inv = 1.f/16384.f;
#pragma unroll
  for (int r = 0; r < 16; ++r){
    int pl = rb + r*4;
    tile[pl][col] = v[(size_t)(n*HWSZ + hw0 + pl)*CCH + o0 + col];
  }
  __syncthreads();
#pragma unroll
  for (int r = 0; r < 16; ++r){
    int ol = rb + r*4;
    int o = o0 + ol;
    float mean = stats[o]*inv;
    float var  = stats[CCH + o]*inv - mean*mean;
    float sc = g[o]*rsqrtf(var + EPSB);
    float sh = bb[o] - mean*sc;
    size_t gi = (size_t)(n*CCH + o)*HWSZ + hw0 + col;
    float val = fmaf(tile[col][ol], sc, sh) + x[gi];
    out[gi] = val > 0.f ? val : 0.f;
  }
}

extern "C" void kernel_launch(void* const* d_in, const int* in_sizes, int n_in,
                              void* d_out, int out_size, void* d_ws, size_t ws_size,
                              hipStream_t stream){
  const float* x     = (const float*)d_in[0];
  const float* tm1_w = (const float*)d_in[1];
  const float* tm1_b = (const float*)d_in[2];
  const float* tr1_w = (const float*)d_in[3];
  const float* tr1_b = (const float*)d_in[4];
  const float* dcn1_w= (const float*)d_in[5];
  const float* bn1_g = (const float*)d_in[6];
  const float* bn1_b = (const float*)d_in[7];
  const float* tm2_w = (const float*)d_in[8];
  const float* tm2_b = (const float*)d_in[9];
  const float* tr2_w = (const float*)d_in[10];
  const float* tr2_b = (const float*)d_in[11];
  const float* dcn2_w= (const float*)d_in[12];
  const float* bn2_g = (const float*)d_in[13];
  const float* bn2_b = (const float*)d_in[14];
  float* out = (float*)d_out;

  char* ws = (char*)d_ws;
  size_t cursor = 0;
  auto alloc = [&](size_t bytes)->char*{
    char* p = ws + cursor; cursor += (bytes + 255) & ~(size_t)255; return p;
  };
  float* xT    = (float*)alloc((size_t)NPIX*CCH*4);
  float* ybuf  = (float*)alloc((size_t)NPIX*CCH*4);
  float* gout  = (float*)alloc((size_t)NPIX*CCH*4);
  float* offb  = (float*)alloc((size_t)NPIX*9*2*4);
  float* woff1 = (float*)alloc(9*6*CCH*4);
  float* woff2 = (float*)alloc(9*6*CCH*4);
  __hip_bfloat16* wg1 = (__hip_bfloat16*)alloc((size_t)CCH*CK*2);
  __hip_bfloat16* wg2 = (__hip_bfloat16*)alloc((size_t)CCH*CK*2);
  float* stats = (float*)alloc(1024*4);
  size_t avail = ws_size > cursor ? ws_size - cursor : 0;
  size_t maxp = avail / ((size_t)CK*2);
  int pchunk = (int)(maxp > NPIX ? NPIX : maxp);
  pchunk &= ~127;
  if (pchunk < 128) pchunk = 128;
  __hip_bfloat16* cols = (__hip_bfloat16*)alloc((size_t)pchunk*CK*2);

  hipMemsetAsync(stats, 0, 1024*4, stream);
  k_transpose_in<<<dim3(64,4,4),256,0,stream>>>(x, xT);
  k_woff_perm<<<54,256,0,stream>>>(tm1_w, tr1_w, woff1);
  k_woff_perm<<<54,256,0,stream>>>(tm2_w, tr2_w, woff2);
  k_wgemm_perm<<<2304,256,0,stream>>>(dcn1_w, wg1);
  k_wgemm_perm<<<2304,256,0,stream>>>(dcn2_w, wg2);

  // ---- layer 1 ----
  k_offsets<<<512,256,0,stream>>>(xT, woff1, tm1_b, tr1_b, offb);
  for (int p0 = 0; p0 < NPIX; p0 += pchunk){
    int pc = (NPIX - p0 < pchunk) ? (NPIX - p0) : pchunk;
    k_im2col<<<pc/32,512,0,stream>>>(xT, offb, cols, p0);
    k_gemm<<<dim3(pc/128,2),256,0,stream>>>(cols, wg1, gout, p0);
  }
  k_bn_stats<<<128,256,0,stream>>>(gout, stats);
  k_bn_apply<<<2048,256,0,stream>>>(gout, stats, bn1_g, bn1_b, ybuf);

  // ---- layer 2 ----
  k_offsets<<<512,256,0,stream>>>(ybuf, woff2, tm2_b, tr2_b, offb);
  for (int p0 = 0; p0 < NPIX; p0 += pchunk){
    int pc = (NPIX - p0 < pchunk) ? (NPIX - p0) : pchunk;
    k_im2col<<<pc/32,512,0,stream>>>(ybuf, offb, cols, p0);
    k_gemm<<<dim3(pc/128,2),256,0,stream>>>(cols, wg2, gout, p0);
  }
  k_bn_stats<<<128,256,0,stream>>>(gout, stats + 512);
  k_final<<<dim3(64,4,4),256,0,stream>>>(gout, stats + 512, bn2_g, bn2_b, x, out);
}

// Round 4
// 247.566 us; speedup vs baseline: 1.5805x; 1.0164x over previous
//
#include <hip/hip_runtime.h>
#include <hip/hip_bf16.h>

#define HH 64
#define WW 64
#define HWSZ 4096
#define NBATCH 4
#define CCH 256
#define NPIX 16384   // NBATCH*HWSZ
#define CK 2304      // 9*256
#define KSPLIT 3
#define KSTEPS 24    // 72/KSPLIT
#define EPSB 1e-5f

typedef __attribute__((ext_vector_type(8))) short bf16x8;
typedef __attribute__((ext_vector_type(4))) float f32x4;

static __device__ __forceinline__ unsigned short f2bf(float f){
  __hip_bfloat16 h = __float2bfloat16(f);
  return *(unsigned short*)&h;
}

// ---------------- transpose x (N,C,H,W) -> xT (N,HW,C) ----------------
__global__ __launch_bounds__(256) void k_transpose_in(const float* __restrict__ x,
                                                      float* __restrict__ xT){
  __shared__ float tile[64][65];
  int hw0 = blockIdx.x * 64;
  int c0  = blockIdx.y * 64;
  int n   = blockIdx.z;
  int t = threadIdx.x;
  int col = t & 63, rb = t >> 6;
#pragma unroll
  for (int r = 0; r < 16; ++r){
    int cl = rb + r*4;
    tile[cl][col] = x[(size_t)(n*CCH + c0 + cl)*HWSZ + hw0 + col];
  }
  __syncthreads();
#pragma unroll
  for (int r = 0; r < 16; ++r){
    int hwl = rb + r*4;
    xT[(size_t)(n*HWSZ + hw0 + hwl)*CCH + c0 + col] = tile[col][hwl];
  }
}

// ---------------- permute offset-conv weights to [k][j][c] (c contiguous) ----------------
__global__ void k_woff_perm(const float* __restrict__ tmw, const float* __restrict__ trw,
                            float* __restrict__ woff){
  int idx = blockIdx.x*256 + threadIdx.x;   // 9*6*256 = 13824
  if (idx >= 9*6*CCH) return;
  int k = idx / (6*CCH); int rem = idx % (6*CCH); int j = rem >> 8; int c = rem & 255;
  float v = (j < 4) ? tmw[(size_t)(j*CCH + c)*9 + k]
                    : trw[(size_t)((j-4)*CCH + c)*9 + k];
  woff[idx] = v;
}

// ---------------- permute dcn weights (Co,C,9) -> bf16 [o][k*256+c] ----------------
__global__ void k_wgemm_perm(const float* __restrict__ w, __hip_bfloat16* __restrict__ wp){
  int idx = blockIdx.x*256 + threadIdx.x;    // 589824 total
  if (idx >= CCH*CK) return;
  int o = idx / CK; int rem = idx % CK; int k = rem >> 8; int c = rem & 255;
  wp[idx] = __float2bfloat16(w[(size_t)(o*CCH + c)*9 + k]);
}

// ---------------- offset generation: conv3x3(6ch) + make_offset, no LDS ----------------
__global__ __launch_bounds__(256) void k_offsets(const float* __restrict__ src,
    const float* __restrict__ wofft, const float* __restrict__ tmb,
    const float* __restrict__ trb, float* __restrict__ off){
  int t = threadIdx.x;
  int wid = t >> 6, lane = t & 63;
  int pbase = blockIdx.x*32 + wid*8;          // 512 blocks * 4 waves * 8 pixels
  int n = pbase >> 12; int hw = pbase & 4095; int h = hw >> 6; int w0 = hw & 63;
  const float* base = src + (size_t)n*HWSZ*CCH + lane*4;

  float acc[8][6];
#pragma unroll
  for (int pi = 0; pi < 8; ++pi)
#pragma unroll
    for (int j = 0; j < 6; ++j) acc[pi][j] = 0.f;

  for (int k = 0; k < 9; ++k){
    int ky = k/3 - 1, kx = k%3 - 1;
    int yy = h + ky;
    if (yy < 0 || yy >= HH) continue;
    float4 wv[6];
#pragma unroll
    for (int j = 0; j < 6; ++j)
      wv[j] = *(const float4*)(wofft + ((k*6 + j) << 8) + lane*4);
#pragma unroll
    for (int pi = 0; pi < 8; ++pi){
      int xx = w0 + pi + kx;
      if (xx < 0 || xx >= WW) continue;
      float4 s4 = *(const float4*)(base + (size_t)(yy*WW + xx)*CCH);
#pragma unroll
      for (int j = 0; j < 6; ++j)
        acc[pi][j] += s4.x*wv[j].x + s4.y*wv[j].y + s4.z*wv[j].z + s4.w*wv[j].w;
    }
  }

#pragma unroll
  for (int pi = 0; pi < 8; ++pi)
#pragma unroll
    for (int j = 0; j < 6; ++j){
      float v = acc[pi][j];
#pragma unroll
      for (int m = 32; m >= 1; m >>= 1) v += __shfl_xor(v, m);
      acc[pi][j] = v;
    }

  float b0 = tmb[0], b1 = tmb[1], b2 = tmb[2], b3 = tmb[3];
  float c0 = trb[0], c1 = trb[1];
  if (lane < 18){
    int k = lane >> 1, comp = lane & 1;
    float dy = (float)(k/3 - 1), dx = (float)(k%3 - 1);
#pragma unroll
    for (int pi = 0; pi < 8; ++pi){
      int p = pbase + pi;
      float val;
      if (comp == 0)
        val = (acc[pi][0] + b0)*dy + (acc[pi][1] + b1)*dx - dy + acc[pi][4] + c0;
      else
        val = (acc[pi][2] + b2)*dy + (acc[pi][3] + b3)*dx - dx + acc[pi][5] + c1;
      off[((size_t)p*9 + k)*2 + comp] = val;
    }
  }
}

// ---------------- im2col v2: 2-phase (uniform setup once -> LDS table; wave gather) ----------------
__global__ __launch_bounds__(512) void k_im2col(const float* __restrict__ src,
    const float* __restrict__ off, __hip_bfloat16* __restrict__ cols, int p_start){
  __shared__ __align__(16) int   t_off[288][4];
  __shared__ __align__(16) float t_w[288][4];
  int t = threadIdx.x;
  int pbase = p_start + blockIdx.x*32;

  if (t < 288){
    int slot = t;
    int pl = slot / 9; int k = slot - pl*9;
    int p = pbase + pl;
    int n = p >> 12; int hw = p & 4095; int h = hw >> 6; int w = hw & 63;
    float2 of = *(const float2*)(off + ((size_t)p*9 + k)*2);
    float py = (float)(h + k/3 - 1) + of.x;
    float px = (float)(w + (k - (k/3)*3) - 1) + of.y;
    float y0f = floorf(py), x0f = floorf(px);
    float wy = py - y0f, wx = px - x0f;
    int y0 = (int)y0f, x0 = (int)x0f;
    int y1 = y0 + 1, x1 = x0 + 1;
    float w00 = (1.f-wy)*(1.f-wx), w01 = (1.f-wy)*wx;
    float w10 = wy*(1.f-wx),       w11 = wy*wx;
    if (y0 < 0 || y0 >= HH) { w00 = 0.f; w01 = 0.f; }
    if (y1 < 0 || y1 >= HH) { w10 = 0.f; w11 = 0.f; }
    if (x0 < 0 || x0 >= WW) { w00 = 0.f; w10 = 0.f; }
    if (x1 < 0 || x1 >= WW) { w01 = 0.f; w11 = 0.f; }
    int y0c = min(max(y0,0),HH-1), y1c = min(max(y1,0),HH-1);
    int x0c = min(max(x0,0),WW-1), x1c = min(max(x1,0),WW-1);
    int pbix = n << 12;
    t_off[slot][0] = (pbix + y0c*WW + x0c) << 10;
    t_off[slot][1] = (pbix + y0c*WW + x1c) << 10;
    t_off[slot][2] = (pbix + y1c*WW + x0c) << 10;
    t_off[slot][3] = (pbix + y1c*WW + x1c) << 10;
    t_w[slot][0] = w00; t_w[slot][1] = w01; t_w[slot][2] = w10; t_w[slot][3] = w11;
  }
  __syncthreads();

  int wid = t >> 6, lane = t & 63;
  int cb = lane << 4;
  const char* sbase = (const char*)src;
  __hip_bfloat16* dbase = cols + (size_t)(pbase - p_start)*CK + (lane << 2);

  for (int slot = wid; slot < 288; slot += 8){
    int4   o  = *(const int4*)t_off[slot];
    float4 wv = *(const float4*)t_w[slot];
    float4 g00 = *(const float4*)(sbase + (size_t)(unsigned)(o.x + cb));
    float4 g01 = *(const float4*)(sbase + (size_t)(unsigned)(o.y + cb));
    float4 g10 = *(const float4*)(sbase + (size_t)(unsigned)(o.z + cb));
    float4 g11 = *(const float4*)(sbase + (size_t)(unsigned)(o.w + cb));
    float v0 = wv.x*g00.x + wv.y*g01.x + wv.z*g10.x + wv.w*g11.x;
    float v1 = wv.x*g00.y + wv.y*g01.y + wv.z*g10.y + wv.w*g11.y;
    float v2 = wv.x*g00.z + wv.y*g01.z + wv.z*g10.z + wv.w*g11.z;
    float v3 = wv.x*g00.w + wv.y*g01.w + wv.z*g10.w + wv.w*g11.w;
    int pl = slot / 9; int k = slot - pl*9;
    ushort4 st;
    st.x = f2bf(v0); st.y = f2bf(v1); st.z = f2bf(v2); st.w = f2bf(v3);
    *(ushort4*)(dbase + (size_t)pl*CK + (k << 8)) = st;
  }
}

// ---------------- GEMM split-K: P[ks][p][o] = sum_{k in slice} cols[p][kc]*wp[o][kc] ----------------
__global__ __launch_bounds__(256) void k_gemm(const __hip_bfloat16* __restrict__ A,
    const __hip_bfloat16* __restrict__ B, float* __restrict__ P, int pc){
  __shared__ __hip_bfloat16 Alds[128*32];
  __shared__ __hip_bfloat16 Blds[128*32];
  int t = threadIdx.x;
  int lane = t & 63, wid = t >> 6;
  int wr = wid >> 1, wc = wid & 1;
  int row0 = blockIdx.x * 128;
  int col0 = blockIdx.y * 128;
  int kofs = blockIdx.z * (KSTEPS*32);
  f32x4 acc[4][4];
#pragma unroll
  for (int i = 0; i < 4; ++i)
#pragma unroll
    for (int j = 0; j < 4; ++j)
      acc[i][j] = (f32x4){0.f,0.f,0.f,0.f};

  int sr = lane >> 2, skq = lane & 3;
  const __hip_bfloat16* aptr0 = A + (size_t)(row0 + (wid*2+0)*16 + sr)*CK + kofs + skq*8;
  const __hip_bfloat16* aptr1 = A + (size_t)(row0 + (wid*2+1)*16 + sr)*CK + kofs + skq*8;
  const __hip_bfloat16* bptr0 = B + (size_t)(col0 + (wid*2+0)*16 + sr)*CK + kofs + skq*8;
  const __hip_bfloat16* bptr1 = B + (size_t)(col0 + (wid*2+1)*16 + sr)*CK + kofs + skq*8;
  __hip_bfloat16* lA0 = Alds + (wid*2+0)*512;
  __hip_bfloat16* lA1 = Alds + (wid*2+1)*512;
  __hip_bfloat16* lB0 = Blds + (wid*2+0)*512;
  __hip_bfloat16* lB1 = Blds + (wid*2+1)*512;

  int fr = lane & 15, fk = (lane >> 4) * 8;

  for (int kt = 0; kt < KSTEPS; ++kt){
#if __has_builtin(__builtin_amdgcn_global_load_lds)
    __builtin_amdgcn_global_load_lds((const __attribute__((address_space(1))) void*)(aptr0),
                                     (__attribute__((address_space(3))) void*)(lA0), 16, 0, 0);
    __builtin_amdgcn_global_load_lds((const __attribute__((address_space(1))) void*)(aptr1),
                                     (__attribute__((address_space(3))) void*)(lA1), 16, 0, 0);
    __builtin_amdgcn_global_load_lds((const __attribute__((address_space(1))) void*)(bptr0),
                                     (__attribute__((address_space(3))) void*)(lB0), 16, 0, 0);
    __builtin_amdgcn_global_load_lds((const __attribute__((address_space(1))) void*)(bptr1),
                                     (__attribute__((address_space(3))) void*)(lB1), 16, 0, 0);
#else
    *(bf16x8*)&lA0[(lane)*8] = *(const bf16x8*)aptr0;
    *(bf16x8*)&lA1[(lane)*8] = *(const bf16x8*)aptr1;
    *(bf16x8*)&lB0[(lane)*8] = *(const bf16x8*)bptr0;
    *(bf16x8*)&lB1[(lane)*8] = *(const bf16x8*)bptr1;
#endif
    aptr0 += 32; aptr1 += 32; bptr0 += 32; bptr1 += 32;
    __syncthreads();
    bf16x8 av[4], bv[4];
#pragma unroll
    for (int mi = 0; mi < 4; ++mi)
      av[mi] = *(const bf16x8*)&Alds[(wr*64 + mi*16 + fr)*32 + fk];
#pragma unroll
    for (int ni = 0; ni < 4; ++ni)
      bv[ni] = *(const bf16x8*)&Blds[(wc*64 + ni*16 + fr)*32 + fk];
#pragma unroll
    for (int mi = 0; mi < 4; ++mi)
#pragma unroll
      for (int ni = 0; ni < 4; ++ni)
        acc[mi][ni] = __builtin_amdgcn_mfma_f32_16x16x32_bf16(av[mi], bv[ni], acc[mi][ni], 0, 0, 0);
    __syncthreads();
  }
  float* Cp = P + (size_t)blockIdx.z * pc * CCH;
  int prow0 = row0 + wr*64;
  int ocol0 = col0 + wc*64;
#pragma unroll
  for (int mi = 0; mi < 4; ++mi)
#pragma unroll
    for (int ni = 0; ni < 4; ++ni){
      int rr = prow0 + mi*16 + (lane>>4)*4;
      int cc = ocol0 + ni*16 + (lane&15);
#pragma unroll
      for (int r = 0; r < 4; ++r)
        Cp[(size_t)(rr + r)*CCH + cc] = acc[mi][ni][r];
    }
}

// ---------------- reduce 3 K-partials -> v, fused per-channel BN stats ----------------
__global__ __launch_bounds__(256) void k_reduce_stats(const float* __restrict__ P,
    float* __restrict__ v, float* __restrict__ stats, int pc){
  int t = threadIdx.x;
  int p0 = blockIdx.x * 64;
  size_t s1 = (size_t)pc * CCH;
  float s = 0.f, ss = 0.f;
#pragma unroll 4
  for (int i = 0; i < 64; ++i){
    size_t idx = (size_t)(p0 + i)*CCH + t;
    float x = P[idx] + P[idx + s1] + P[idx + 2*s1];
    v[idx] = x;
    s += x; ss += x*x;
  }
  atomicAdd(&stats[t], s);
  atomicAdd(&stats[CCH + t], ss);
}

// ---------------- BN apply + ReLU (channels-last in/out) ----------------
__global__ __launch_bounds__(256) void k_bn_apply(const float* __restrict__ v,
    const float* __restrict__ stats, const float* __restrict__ g,
    const float* __restrict__ bb, float* __restrict__ y){
  const float inv = 1.f/16384.f;
  for (size_t i = (size_t)blockIdx.x*256 + threadIdx.x; i < (size_t)NPIX*CCH;
       i += (size_t)gridDim.x*256){
    int c = (int)(i & 255);
    float mean = stats[c]*inv;
    float var  = stats[CCH + c]*inv - mean*mean;
    float sc = g[c]*rsqrtf(var + EPSB);
    float sh = bb[c] - mean*sc;
    float val = fmaf(v[i], sc, sh);
    y[i] = val > 0.f ? val : 0.f;
  }
}

// ---------------- final: BN2 + residual + ReLU, transpose to NCHW ----------------
__global__ __launch_bounds__(256) void k_final(const float* __restrict__ v,
    const float* __restrict__ stats, const float* __restrict__ g,
    const float* __restrict__ bb, const float* __restrict__ x,
    float* __restrict__ out){
  __shared__ float tile[64][65];
  int hw0 = blockIdx.x * 64;
  int o0  = blockIdx.y * 64;
  int n   = blockIdx.z;
  int t = threadIdx.x;
  int col = t & 63, rb = t >> 6;
  const float inv = 1.f/16384.f;
#pragma unroll
  for (int r = 0; r < 16; ++r){
    int pl = rb + r*4;
    tile[pl][col] = v[(size_t)(n*HWSZ + hw0 + pl)*CCH + o0 + col];
  }
  __syncthreads();
#pragma unroll
  for (int r = 0; r < 16; ++r){
    int ol = rb + r*4;
    int o = o0 + ol;
    float mean = stats[o]*inv;
    float var  = stats[CCH + o]*inv - mean*mean;
    float sc = g[o]*rsqrtf(var + EPSB);
    float sh = bb[o] - mean*sc;
    size_t gi = (size_t)(n*CCH + o)*HWSZ + hw0 + col;
    float val = fmaf(tile[col][ol], sc, sh) + x[gi];
    out[gi] = val > 0.f ? val : 0.f;
  }
}

extern "C" void kernel_launch(void* const* d_in, const int* in_sizes, int n_in,
                              void* d_out, int out_size, void* d_ws, size_t ws_size,
                              hipStream_t stream){
  const float* x     = (const float*)d_in[0];
  const float* tm1_w = (const float*)d_in[1];
  const float* tm1_b = (const float*)d_in[2];
  const float* tr1_w = (const float*)d_in[3];
  const float* tr1_b = (const float*)d_in[4];
  const float* dcn1_w= (const float*)d_in[5];
  const float* bn1_g = (const float*)d_in[6];
  const float* bn1_b = (const float*)d_in[7];
  const float* tm2_w = (const float*)d_in[8];
  const float* tm2_b = (const float*)d_in[9];
  const float* tr2_w = (const float*)d_in[10];
  const float* tr2_b = (const float*)d_in[11];
  const float* dcn2_w= (const float*)d_in[12];
  const float* bn2_g = (const float*)d_in[13];
  const float* bn2_b = (const float*)d_in[14];
  float* out = (float*)d_out;

  char* ws = (char*)d_ws;
  size_t cursor = 0;
  auto alloc = [&](size_t bytes)->char*{
    char* p = ws + cursor; cursor += (bytes + 255) & ~(size_t)255; return p;
  };
  float* xT    = (float*)alloc((size_t)NPIX*CCH*4);
  float* ybuf  = (float*)alloc((size_t)NPIX*CCH*4);
  float* gout  = (float*)alloc((size_t)NPIX*CCH*4);
  float* offb  = (float*)alloc((size_t)NPIX*9*2*4);
  float* woff1 = (float*)alloc(9*6*CCH*4);
  float* woff2 = (float*)alloc(9*6*CCH*4);
  __hip_bfloat16* wg1 = (__hip_bfloat16*)alloc((size_t)CCH*CK*2);
  __hip_bfloat16* wg2 = (__hip_bfloat16*)alloc((size_t)CCH*CK*2);
  float* stats = (float*)alloc(1024*4);
  size_t avail = ws_size > cursor ? ws_size - cursor : 0;
  // per-pixel chunk bytes: cols (CK*2 = 4608) + 3 partials (3*CCH*4 = 3072)
  size_t maxp = avail / ((size_t)CK*2 + (size_t)KSPLIT*CCH*4);
  int pchunk = (int)(maxp > NPIX ? NPIX : maxp);
  pchunk &= ~127;
  if (pchunk < 128) pchunk = 128;
  __hip_bfloat16* cols = (__hip_bfloat16*)alloc((size_t)pchunk*CK*2);
  float* pbuf  = (float*)alloc((size_t)KSPLIT*pchunk*CCH*4);

  hipMemsetAsync(stats, 0, 1024*4, stream);
  k_transpose_in<<<dim3(64,4,4),256,0,stream>>>(x, xT);
  k_woff_perm<<<54,256,0,stream>>>(tm1_w, tr1_w, woff1);
  k_woff_perm<<<54,256,0,stream>>>(tm2_w, tr2_w, woff2);
  k_wgemm_perm<<<2304,256,0,stream>>>(dcn1_w, wg1);
  k_wgemm_perm<<<2304,256,0,stream>>>(dcn2_w, wg2);

  // ---- layer 1 ----
  k_offsets<<<512,256,0,stream>>>(xT, woff1, tm1_b, tr1_b, offb);
  for (int p0 = 0; p0 < NPIX; p0 += pchunk){
    int pc = (NPIX - p0 < pchunk) ? (NPIX - p0) : pchunk;
    k_im2col<<<pc/32,512,0,stream>>>(xT, offb, cols, p0);
    k_gemm<<<dim3(pc/128,2,KSPLIT),256,0,stream>>>(cols, wg1, pbuf, pc);
    k_reduce_stats<<<pc/64,256,0,stream>>>(pbuf, gout + (size_t)p0*CCH, stats, pc);
  }
  k_bn_apply<<<2048,256,0,stream>>>(gout, stats, bn1_g, bn1_b, ybuf);

  // ---- layer 2 ----
  k_offsets<<<512,256,0,stream>>>(ybuf, woff2, tm2_b, tr2_b, offb);
  for (int p0 = 0; p0 < NPIX; p0 += pchunk){
    int pc = (NPIX - p0 < pchunk) ? (NPIX - p0) : pchunk;
    k_im2col<<<pc/32,512,0,stream>>>(ybuf, offb, cols, p0);
    k_gemm<<<dim3(pc/128,2,KSPLIT),256,0,stream>>>(cols, wg2, pbuf, pc);
    k_reduce_stats<<<pc/64,256,0,stream>>>(pbuf, gout + (size_t)p0*CCH, stats + 512, pc);
  }
  k_final<<<dim3(64,4,4),256,0,stream>>>(gout, stats + 512, bn2_g, bn2_b, x, out);
}

// Round 5
// 230.549 us; speedup vs baseline: 1.6971x; 1.0738x over previous
//
#include <hip/hip_runtime.h>
#include <hip/hip_bf16.h>

#define HH 64
#define WW 64
#define HWSZ 4096
#define NBATCH 4
#define CCH 256
#define NPIX 16384   // NBATCH*HWSZ
#define CK 2304      // 9*256
#define KSPLIT 3
#define EPSB 1e-5f

typedef __attribute__((ext_vector_type(8))) short bf16x8;
typedef __attribute__((ext_vector_type(4))) float f32x4;

static __device__ __forceinline__ unsigned short f2bf(float f){
  __hip_bfloat16 h = __float2bfloat16(f);
  return *(unsigned short*)&h;
}

// ---------------- transpose x (N,C,H,W) -> xT (N,HW,C) ----------------
__global__ __launch_bounds__(256) void k_transpose_in(const float* __restrict__ x,
                                                      float* __restrict__ xT){
  __shared__ float tile[64][65];
  int hw0 = blockIdx.x * 64;
  int c0  = blockIdx.y * 64;
  int n   = blockIdx.z;
  int t = threadIdx.x;
  int col = t & 63, rb = t >> 6;
#pragma unroll
  for (int r = 0; r < 16; ++r){
    int cl = rb + r*4;
    tile[cl][col] = x[(size_t)(n*CCH + c0 + cl)*HWSZ + hw0 + col];
  }
  __syncthreads();
#pragma unroll
  for (int r = 0; r < 16; ++r){
    int hwl = rb + r*4;
    xT[(size_t)(n*HWSZ + hw0 + hwl)*CCH + c0 + col] = tile[col][hwl];
  }
}

// ---------------- permute offset-conv weights to [k][j][c] (c contiguous) ----------------
__global__ void k_woff_perm(const float* __restrict__ tmw, const float* __restrict__ trw,
                            float* __restrict__ woff){
  int idx = blockIdx.x*256 + threadIdx.x;   // 9*6*256 = 13824
  if (idx >= 9*6*CCH) return;
  int k = idx / (6*CCH); int rem = idx % (6*CCH); int j = rem >> 8; int c = rem & 255;
  float v = (j < 4) ? tmw[(size_t)(j*CCH + c)*9 + k]
                    : trw[(size_t)((j-4)*CCH + c)*9 + k];
  woff[idx] = v;
}

// ---------------- pack dcn weights (Co,C,3,3) -> bf16 blocks [tap*8+cb][o][32ch],
// with LDS XOR-swizzle baked in: logical elem m stored at m ^ (8*(o&3)) ----------------
__global__ void k_wgemm_perm(const float* __restrict__ w, __hip_bfloat16* __restrict__ wp){
  int idx = blockIdx.x*256 + threadIdx.x;    // 589824 total
  if (idx >= CCH*CK) return;
  int blk = idx >> 13;        // tap*8 + cb  (72 blocks of 8192 elems)
  int e   = idx & 8191;
  int o   = e >> 5;
  int el  = e & 31;
  int tap = blk >> 3, cb = blk & 7;
  int c   = cb*32 + (el ^ ((o & 3) << 3));
  wp[idx] = __float2bfloat16(w[(size_t)o*CK + c*9 + tap]);
}

// ---------------- offset generation: conv3x3(6ch) + make_offset, no LDS ----------------
__global__ __launch_bounds__(256) void k_offsets(const float* __restrict__ src,
    const float* __restrict__ wofft, const float* __restrict__ tmb,
    const float* __restrict__ trb, float* __restrict__ off){
  int t = threadIdx.x;
  int wid = t >> 6, lane = t & 63;
  int pbase = blockIdx.x*32 + wid*8;          // 512 blocks * 4 waves * 8 pixels
  int n = pbase >> 12; int hw = pbase & 4095; int h = hw >> 6; int w0 = hw & 63;
  const float* base = src + (size_t)n*HWSZ*CCH + lane*4;

  float acc[8][6];
#pragma unroll
  for (int pi = 0; pi < 8; ++pi)
#pragma unroll
    for (int j = 0; j < 6; ++j) acc[pi][j] = 0.f;

  for (int k = 0; k < 9; ++k){
    int ky = k/3 - 1, kx = k%3 - 1;
    int yy = h + ky;
    if (yy < 0 || yy >= HH) continue;
    float4 wv[6];
#pragma unroll
    for (int j = 0; j < 6; ++j)
      wv[j] = *(const float4*)(wofft + ((k*6 + j) << 8) + lane*4);
#pragma unroll
    for (int pi = 0; pi < 8; ++pi){
      int xx = w0 + pi + kx;
      if (xx < 0 || xx >= WW) continue;
      float4 s4 = *(const float4*)(base + (size_t)(yy*WW + xx)*CCH);
#pragma unroll
      for (int j = 0; j < 6; ++j)
        acc[pi][j] += s4.x*wv[j].x + s4.y*wv[j].y + s4.z*wv[j].z + s4.w*wv[j].w;
    }
  }

#pragma unroll
  for (int pi = 0; pi < 8; ++pi)
#pragma unroll
    for (int j = 0; j < 6; ++j){
      float v = acc[pi][j];
#pragma unroll
      for (int m = 32; m >= 1; m >>= 1) v += __shfl_xor(v, m);
      acc[pi][j] = v;
    }

  float b0 = tmb[0], b1 = tmb[1], b2 = tmb[2], b3 = tmb[3];
  float c0 = trb[0], c1 = trb[1];
  if (lane < 18){
    int k = lane >> 1, comp = lane & 1;
    float dy = (float)(k/3 - 1), dx = (float)(k%3 - 1);
#pragma unroll
    for (int pi = 0; pi < 8; ++pi){
      int p = pbase + pi;
      float val;
      if (comp == 0)
        val = (acc[pi][0] + b0)*dy + (acc[pi][1] + b1)*dx - dy + acc[pi][4] + c0;
      else
        val = (acc[pi][2] + b2)*dy + (acc[pi][3] + b3)*dx - dx + acc[pi][5] + c1;
      off[((size_t)p*9 + k)*2 + comp] = val;
    }
  }
}

// ---------------- fused deform-im2col + GEMM, split-K over taps ----------------
// Grid (NPIX/64, KSPLIT), 512 threads (8 waves). Block: 64 px x 256 och, K-slice =
// 3 taps x 256 ch = 24 steps of 32ch. A (64x32) gathered global->reg->LDS with 1-step
// pipeline; B (256x32) via global_load_lds from pre-swizzled wp. Both LDS tiles
// XOR-swizzled (elem m <-> m ^ 8*(row&3)).
__global__ __launch_bounds__(512) void k_dcn(const float* __restrict__ src,
    const float* __restrict__ off, const __hip_bfloat16* __restrict__ wp,
    float* __restrict__ P){
  __shared__ __hip_bfloat16 Al[64*32];
  __shared__ __hip_bfloat16 Bl[256*32];
  __shared__ __align__(16) int   t_off[192][4];
  __shared__ __align__(16) float t_w[192][4];

  int t = threadIdx.x;
  int z = blockIdx.y;
  int pbase = blockIdx.x * 64;

  // ---- setup: 192 slots = 64 px x 3 taps ----
  if (t < 192){
    int px = t / 3, ti = t - px*3;
    int k = z*3 + ti;
    int p = pbase + px;
    int n = p >> 12; int hw = p & 4095; int h = hw >> 6; int w = hw & 63;
    float2 of = *(const float2*)(off + ((size_t)p*9 + k)*2);
    float py = (float)(h + k/3 - 1) + of.x;
    float px_ = (float)(w + (k - (k/3)*3) - 1) + of.y;
    float y0f = floorf(py), x0f = floorf(px_);
    float wy = py - y0f, wx = px_ - x0f;
    int y0 = (int)y0f, x0 = (int)x0f;
    int y1 = y0 + 1, x1 = x0 + 1;
    float w00 = (1.f-wy)*(1.f-wx), w01 = (1.f-wy)*wx;
    float w10 = wy*(1.f-wx),       w11 = wy*wx;
    if (y0 < 0 || y0 >= HH) { w00 = 0.f; w01 = 0.f; }
    if (y1 < 0 || y1 >= HH) { w10 = 0.f; w11 = 0.f; }
    if (x0 < 0 || x0 >= WW) { w00 = 0.f; w10 = 0.f; }
    if (x1 < 0 || x1 >= WW) { w01 = 0.f; w11 = 0.f; }
    int y0c = min(max(y0,0),HH-1), y1c = min(max(y1,0),HH-1);
    int x0c = min(max(x0,0),WW-1), x1c = min(max(x1,0),WW-1);
    int pbix = n << 12;
    t_off[t][0] = (pbix + y0c*WW + x0c) << 10;   // byte offset (256ch*4B per pixel)
    t_off[t][1] = (pbix + y0c*WW + x1c) << 10;
    t_off[t][2] = (pbix + y1c*WW + x0c) << 10;
    t_off[t][3] = (pbix + y1c*WW + x1c) << 10;
    t_w[t][0] = w00; t_w[t][1] = w01; t_w[t][2] = w10; t_w[t][3] = w11;
  }
  __syncthreads();

  int wid = t >> 6, lane = t & 63;
  int pxl = t >> 3, q = t & 7;          // gather role: pixel-local, channel-quad
  int px3 = pxl * 3, qb = q * 16;
  const char* sbase = (const char*)src;

  // A LDS write address (bytes), swizzled
  int abyte = pxl*64 + ((q*8) ^ ((pxl & 3) << 4));

  // frag read bases (bytes), constant over loop
  int kq = lane >> 4, fr = lane & 15;
  int abr[4], bbr[2];
#pragma unroll
  for (int mi = 0; mi < 4; ++mi){
    int apx = mi*16 + fr;
    abr[mi] = apx*64 + ((kq*16) ^ ((apx & 3) << 4));
  }
#pragma unroll
  for (int ni = 0; ni < 2; ++ni){
    int o = wid*32 + ni*16 + fr;
    bbr[ni] = o*64 + ((kq*16) ^ ((o & 3) << 4));
  }

  f32x4 acc[4][2];
#pragma unroll
  for (int i = 0; i < 4; ++i)
#pragma unroll
    for (int j = 0; j < 2; ++j)
      acc[i][j] = (f32x4){0.f,0.f,0.f,0.f};

  // ---- prologue gather (kt = 0) ----
  float4 ga, gb, gc, gd, wv;
  {
    int4 o4 = *(const int4*)t_off[px3];
    wv = *(const float4*)t_w[px3];
    ga = *(const float4*)(sbase + (size_t)(unsigned)(o4.x + qb));
    gb = *(const float4*)(sbase + (size_t)(unsigned)(o4.y + qb));
    gc = *(const float4*)(sbase + (size_t)(unsigned)(o4.z + qb));
    gd = *(const float4*)(sbase + (size_t)(unsigned)(o4.w + qb));
  }

  const char* wpz = (const char*)wp + (size_t)(z*24) * 16384;

  for (int kt = 0; kt < 24; ++kt){
    // B stage for this step (LDS free post previous barrier2)
    const char* bsrc = wpz + (size_t)kt*16384 + wid*2048 + lane*16;
    char* bdst = (char*)Bl + wid*2048;
#if __has_builtin(__builtin_amdgcn_global_load_lds)
    __builtin_amdgcn_global_load_lds((const __attribute__((address_space(1))) void*)bsrc,
                                     (__attribute__((address_space(3))) void*)bdst, 16, 0, 0);
    __builtin_amdgcn_global_load_lds((const __attribute__((address_space(1))) void*)(bsrc + 1024),
                                     (__attribute__((address_space(3))) void*)(bdst + 1024), 16, 0, 0);
#else
    *(bf16x8*)(bdst + lane*16)        = *(const bf16x8*)bsrc;
    *(bf16x8*)(bdst + 1024 + lane*16) = *(const bf16x8*)(bsrc + 1024);
#endif
    // consume current gather -> bf16 quad
    float v0 = wv.x*ga.x + wv.y*gb.x + wv.z*gc.x + wv.w*gd.x;
    float v1 = wv.x*ga.y + wv.y*gb.y + wv.z*gc.y + wv.w*gd.y;
    float v2 = wv.x*ga.z + wv.y*gb.z + wv.z*gc.z + wv.w*gd.z;
    float v3 = wv.x*ga.w + wv.y*gb.w + wv.z*gc.w + wv.w*gd.w;
    ushort4 st;
    st.x = f2bf(v0); st.y = f2bf(v1); st.z = f2bf(v2); st.w = f2bf(v3);

    // issue next-step gather (hides under barrier + MFMA)
    {
      int ktn = (kt + 1 < 24) ? kt + 1 : 0;
      int slot = px3 + (ktn >> 3);
      int chb = ((ktn & 7) << 7) + qb;
      int4 o4 = *(const int4*)t_off[slot];
      wv = *(const float4*)t_w[slot];
      ga = *(const float4*)(sbase + (size_t)(unsigned)(o4.x + chb));
      gb = *(const float4*)(sbase + (size_t)(unsigned)(o4.y + chb));
      gc = *(const float4*)(sbase + (size_t)(unsigned)(o4.z + chb));
      gd = *(const float4*)(sbase + (size_t)(unsigned)(o4.w + chb));
    }

    *(ushort4*)((char*)Al + abyte) = st;
    __syncthreads();              // drains A ds_write + B global_load_lds

    bf16x8 av[4], bv[2];
#pragma unroll
    for (int mi = 0; mi < 4; ++mi)
      av[mi] = *(const bf16x8*)((const char*)Al + abr[mi]);
#pragma unroll
    for (int ni = 0; ni < 2; ++ni)
      bv[ni] = *(const bf16x8*)((const char*)Bl + bbr[ni]);
#pragma unroll
    for (int mi = 0; mi < 4; ++mi)
#pragma unroll
      for (int ni = 0; ni < 2; ++ni)
        acc[mi][ni] = __builtin_amdgcn_mfma_f32_16x16x32_bf16(av[mi], bv[ni], acc[mi][ni], 0, 0, 0);
    __syncthreads();
  }

  float* Cp = P + (size_t)z * NPIX * CCH;
#pragma unroll
  for (int mi = 0; mi < 4; ++mi)
#pragma unroll
    for (int ni = 0; ni < 2; ++ni){
      int rr = pbase + mi*16 + (lane>>4)*4;
      int cc = wid*32 + ni*16 + (lane&15);
#pragma unroll
      for (int r = 0; r < 4; ++r)
        Cp[(size_t)(rr + r)*CCH + cc] = acc[mi][ni][r];
    }
}

// ---------------- reduce 3 K-partials -> v, fused per-channel BN stats ----------------
__global__ __launch_bounds__(256) void k_reduce_stats(const float* __restrict__ P,
    float* __restrict__ v, float* __restrict__ stats){
  int t = threadIdx.x;
  int p0 = blockIdx.x * 64;
  const size_t s1 = (size_t)NPIX * CCH;
  float s = 0.f, ss = 0.f;
#pragma unroll 4
  for (int i = 0; i < 64; ++i){
    size_t idx = (size_t)(p0 + i)*CCH + t;
    float x = P[idx] + P[idx + s1] + P[idx + 2*s1];
    v[idx] = x;
    s += x; ss += x*x;
  }
  atomicAdd(&stats[t], s);
  atomicAdd(&stats[CCH + t], ss);
}

// ---------------- BN apply + ReLU (channels-last in/out) ----------------
__global__ __launch_bounds__(256) void k_bn_apply(const float* __restrict__ v,
    const float* __restrict__ stats, const float* __restrict__ g,
    const float* __restrict__ bb, float* __restrict__ y){
  const float inv = 1.f/16384.f;
  for (size_t i = (size_t)blockIdx.x*256 + threadIdx.x; i < (size_t)NPIX*CCH;
       i += (size_t)gridDim.x*256){
    int c = (int)(i & 255);
    float mean = stats[c]*inv;
    float var  = stats[CCH + c]*inv - mean*mean;
    float sc = g[c]*rsqrtf(var + EPSB);
    float sh = bb[c] - mean*sc;
    float val = fmaf(v[i], sc, sh);
    y[i] = val > 0.f ? val : 0.f;
  }
}

// ---------------- final: BN2 + residual + ReLU, transpose to NCHW ----------------
__global__ __launch_bounds__(256) void k_final(const float* __restrict__ v,
    const float* __restrict__ stats, const float* __restrict__ g,
    const float* __restrict__ bb, const float* __restrict__ x,
    float* __restrict__ out){
  __shared__ float tile[64][65];
  int hw0 = blockIdx.x * 64;
  int o0  = blockIdx.y * 64;
  int n   = blockIdx.z;
  int t = threadIdx.x;
  int col = t & 63, rb = t >> 6;
  const float inv = 1.f/16384.f;
#pragma unroll
  for (int r = 0; r < 16; ++r){
    int pl = rb + r*4;
    tile[pl][col] = v[(size_t)(n*HWSZ + hw0 + pl)*CCH + o0 + col];
  }
  __syncthreads();
#pragma unroll
  for (int r = 0; r < 16; ++r){
    int ol = rb + r*4;
    int o = o0 + ol;
    float mean = stats[o]*inv;
    float var  = stats[CCH + o]*inv - mean*mean;
    float sc = g[o]*rsqrtf(var + EPSB);
    float sh = bb[o] - mean*sc;
    size_t gi = (size_t)(n*CCH + o)*HWSZ + hw0 + col;
    float val = fmaf(tile[col][ol], sc, sh) + x[gi];
    out[gi] = val > 0.f ? val : 0.f;
  }
}

extern "C" void kernel_launch(void* const* d_in, const int* in_sizes, int n_in,
                              void* d_out, int out_size, void* d_ws, size_t ws_size,
                              hipStream_t stream){
  const float* x     = (const float*)d_in[0];
  const float* tm1_w = (const float*)d_in[1];
  const float* tm1_b = (const float*)d_in[2];
  const float* tr1_w = (const float*)d_in[3];
  const float* tr1_b = (const float*)d_in[4];
  const float* dcn1_w= (const float*)d_in[5];
  const float* bn1_g = (const float*)d_in[6];
  const float* bn1_b = (const float*)d_in[7];
  const float* tm2_w = (const float*)d_in[8];
  const float* tm2_b = (const float*)d_in[9];
  const float* tr2_w = (const float*)d_in[10];
  const float* tr2_b = (const float*)d_in[11];
  const float* dcn2_w= (const float*)d_in[12];
  const float* bn2_g = (const float*)d_in[13];
  const float* bn2_b = (const float*)d_in[14];
  float* out = (float*)d_out;

  char* ws = (char*)d_ws;
  size_t cursor = 0;
  auto alloc = [&](size_t bytes)->char*{
    char* p = ws + cursor; cursor += (bytes + 255) & ~(size_t)255; return p;
  };
  float* xT    = (float*)alloc((size_t)NPIX*CCH*4);
  float* ybuf  = (float*)alloc((size_t)NPIX*CCH*4);
  float* gout  = (float*)alloc((size_t)NPIX*CCH*4);
  float* offb  = (float*)alloc((size_t)NPIX*9*2*4);
  float* woff1 = (float*)alloc(9*6*CCH*4);
  float* woff2 = (float*)alloc(9*6*CCH*4);
  __hip_bfloat16* wg1 = (__hip_bfloat16*)alloc((size_t)CCH*CK*2);
  __hip_bfloat16* wg2 = (__hip_bfloat16*)alloc((size_t)CCH*CK*2);
  float* stats = (float*)alloc(1024*4);
  float* pbuf  = (float*)alloc((size_t)KSPLIT*NPIX*CCH*4);

  hipMemsetAsync(stats, 0, 1024*4, stream);
  k_transpose_in<<<dim3(64,4,4),256,0,stream>>>(x, xT);
  k_woff_perm<<<54,256,0,stream>>>(tm1_w, tr1_w, woff1);
  k_woff_perm<<<54,256,0,stream>>>(tm2_w, tr2_w, woff2);
  k_wgemm_perm<<<2304,256,0,stream>>>(dcn1_w, wg1);
  k_wgemm_perm<<<2304,256,0,stream>>>(dcn2_w, wg2);

  // ---- layer 1 ----
  k_offsets<<<512,256,0,stream>>>(xT, woff1, tm1_b, tr1_b, offb);
  k_dcn<<<dim3(NPIX/64,KSPLIT),512,0,stream>>>(xT, offb, wg1, pbuf);
  k_reduce_stats<<<NPIX/64,256,0,stream>>>(pbuf, gout, stats);
  k_bn_apply<<<2048,256,0,stream>>>(gout, stats, bn1_g, bn1_b, ybuf);

  // ---- layer 2 ----
  k_offsets<<<512,256,0,stream>>>(ybuf, woff2, tm2_b, tr2_b, offb);
  k_dcn<<<dim3(NPIX/64,KSPLIT),512,0,stream>>>(ybuf, offb, wg2, pbuf);
  k_reduce_stats<<<NPIX/64,256,0,stream>>>(pbuf, gout, stats + 512);
  k_final<<<dim3(64,4,4),256,0,stream>>>(gout, stats + 512, bn2_g, bn2_b, x, out);
}

// Round 6
// 219.263 us; speedup vs baseline: 1.7845x; 1.0515x over previous
//
#include <hip/hip_runtime.h>
#include <hip/hip_bf16.h>

#define HH 64
#define WW 64
#define HWSZ 4096
#define NBATCH 4
#define CCH 256
#define NPIX 16384   // NBATCH*HWSZ
#define CK 2304      // 9*256
#define EPSB 1e-5f

typedef __attribute__((ext_vector_type(8))) short bf16x8;
typedef __attribute__((ext_vector_type(4))) float f32x4;

static __device__ __forceinline__ unsigned short f2bf(float f){
  __hip_bfloat16 h = __float2bfloat16(f);
  return *(unsigned short*)&h;
}

#if __has_builtin(__builtin_amdgcn_global_load_lds)
#define GLD(S,D) __builtin_amdgcn_global_load_lds((const __attribute__((address_space(1))) void*)(S), \
                                                  (__attribute__((address_space(3))) void*)(D), 16, 0, 0)
#else
#define GLD(S,D) (*(bf16x8*)((char*)(D) + lane*16) = *(const bf16x8*)(S))
#endif

// ---------------- transpose x (N,C,H,W) -> xT (N,HW,C) ----------------
__global__ __launch_bounds__(256) void k_transpose_in(const float* __restrict__ x,
                                                      float* __restrict__ xT){
  __shared__ float tile[64][65];
  int hw0 = blockIdx.x * 64;
  int c0  = blockIdx.y * 64;
  int n   = blockIdx.z;
  int t = threadIdx.x;
  int col = t & 63, rb = t >> 6;
#pragma unroll
  for (int r = 0; r < 16; ++r){
    int cl = rb + r*4;
    tile[cl][col] = x[(size_t)(n*CCH + c0 + cl)*HWSZ + hw0 + col];
  }
  __syncthreads();
#pragma unroll
  for (int r = 0; r < 16; ++r){
    int hwl = rb + r*4;
    xT[(size_t)(n*HWSZ + hw0 + hwl)*CCH + c0 + col] = tile[col][hwl];
  }
}

// ---------------- permute offset-conv weights to [k][j][c] (c contiguous) ----------------
__global__ void k_woff_perm(const float* __restrict__ tmw, const float* __restrict__ trw,
                            float* __restrict__ woff){
  int idx = blockIdx.x*256 + threadIdx.x;   // 9*6*256 = 13824
  if (idx >= 9*6*CCH) return;
  int k = idx / (6*CCH); int rem = idx % (6*CCH); int j = rem >> 8; int c = rem & 255;
  float v = (j < 4) ? tmw[(size_t)(j*CCH + c)*9 + k]
                    : trw[(size_t)((j-4)*CCH + c)*9 + k];
  woff[idx] = v;
}

// ---------------- pack dcn weights (Co,C,3,3) -> bf16 blocks [tap*8+cb][o][32ch],
// with LDS XOR-swizzle baked in: logical elem m stored at m ^ (8*(o&3)) ----------------
__global__ void k_wgemm_perm(const float* __restrict__ w, __hip_bfloat16* __restrict__ wp){
  int idx = blockIdx.x*256 + threadIdx.x;    // 589824 total
  if (idx >= CCH*CK) return;
  int blk = idx >> 13;        // tap*8 + cb  (72 blocks of 8192 elems)
  int e   = idx & 8191;
  int o   = e >> 5;
  int el  = e & 31;
  int tap = blk >> 3, cb = blk & 7;
  int c   = cb*32 + (el ^ ((o & 3) << 3));
  wp[idx] = __float2bfloat16(w[(size_t)o*CK + c*9 + tap]);
}

// ---------------- offset generation: conv3x3(6ch) + make_offset, no LDS ----------------
__global__ __launch_bounds__(256) void k_offsets(const float* __restrict__ src,
    const float* __restrict__ wofft, const float* __restrict__ tmb,
    const float* __restrict__ trb, float* __restrict__ off){
  int t = threadIdx.x;
  int wid = t >> 6, lane = t & 63;
  int pbase = blockIdx.x*32 + wid*8;          // 512 blocks * 4 waves * 8 pixels
  int n = pbase >> 12; int hw = pbase & 4095; int h = hw >> 6; int w0 = hw & 63;
  const float* base = src + (size_t)n*HWSZ*CCH + lane*4;

  float acc[8][6];
#pragma unroll
  for (int pi = 0; pi < 8; ++pi)
#pragma unroll
    for (int j = 0; j < 6; ++j) acc[pi][j] = 0.f;

  for (int k = 0; k < 9; ++k){
    int ky = k/3 - 1, kx = k%3 - 1;
    int yy = h + ky;
    if (yy < 0 || yy >= HH) continue;
    float4 wv[6];
#pragma unroll
    for (int j = 0; j < 6; ++j)
      wv[j] = *(const float4*)(wofft + ((k*6 + j) << 8) + lane*4);
#pragma unroll
    for (int pi = 0; pi < 8; ++pi){
      int xx = w0 + pi + kx;
      if (xx < 0 || xx >= WW) continue;
      float4 s4 = *(const float4*)(base + (size_t)(yy*WW + xx)*CCH);
#pragma unroll
      for (int j = 0; j < 6; ++j)
        acc[pi][j] += s4.x*wv[j].x + s4.y*wv[j].y + s4.z*wv[j].z + s4.w*wv[j].w;
    }
  }

#pragma unroll
  for (int pi = 0; pi < 8; ++pi)
#pragma unroll
    for (int j = 0; j < 6; ++j){
      float v = acc[pi][j];
#pragma unroll
      for (int m = 32; m >= 1; m >>= 1) v += __shfl_xor(v, m);
      acc[pi][j] = v;
    }

  float b0 = tmb[0], b1 = tmb[1], b2 = tmb[2], b3 = tmb[3];
  float c0 = trb[0], c1 = trb[1];
  if (lane < 18){
    int k = lane >> 1, comp = lane & 1;
    float dy = (float)(k/3 - 1), dx = (float)(k%3 - 1);
#pragma unroll
    for (int pi = 0; pi < 8; ++pi){
      int p = pbase + pi;
      float val;
      if (comp == 0)
        val = (acc[pi][0] + b0)*dy + (acc[pi][1] + b1)*dx - dy + acc[pi][4] + c0;
      else
        val = (acc[pi][2] + b2)*dy + (acc[pi][3] + b3)*dx - dx + acc[pi][5] + c1;
      off[((size_t)p*9 + k)*2 + comp] = val;
    }
  }
}

// ---------------- fused deform-im2col + GEMM, all 9 taps per block ----------------
// Grid 256 blocks (XCD-swizzled), 512 threads. Tile: 64 px x 256 och, K = 9 taps x
// 256 ch = 72 steps of 32ch (tap-major). A (64x32) gathered global->reg->LDS; B
// (256x32) global_load_lds from pre-swizzled wp. BOTH double-buffered -> one
// __syncthreads per step; loads issued right after the barrier, consumed just
// before the next (full-step latency window). Gathers issued before B-loads so
// the convert's vmcnt wait is counted, not 0. Writes gout directly (no split-K).
__global__ __launch_bounds__(512) void k_dcn(const float* __restrict__ src,
    const float* __restrict__ off, const __hip_bfloat16* __restrict__ wp,
    float* __restrict__ gout){
  __shared__ __hip_bfloat16 Al[2*64*32];     // 2 x 4KB
  __shared__ __hip_bfloat16 Bl[2*256*32];    // 2 x 16KB
  __shared__ __align__(16) int   t_off[576][4];
  __shared__ __align__(16) float t_w[576][4];

  int t = threadIdx.x;
  int bid = blockIdx.x;
  int tile = (bid & 7)*32 + (bid >> 3);      // XCD-bijective: 32 contiguous tiles/XCD
  int pbase = tile * 64;

  // ---- setup: 576 slots = 64 px x 9 taps ----
  for (int s = t; s < 576; s += 512){
    int px = s / 9, k = s - px*9;
    int p = pbase + px;
    int n = p >> 12; int hw = p & 4095; int h = hw >> 6; int w = hw & 63;
    float2 of = *(const float2*)(off + ((size_t)p*9 + k)*2);
    float py = (float)(h + k/3 - 1) + of.x;
    float px_ = (float)(w + (k - (k/3)*3) - 1) + of.y;
    float y0f = floorf(py), x0f = floorf(px_);
    float wy = py - y0f, wx = px_ - x0f;
    int y0 = (int)y0f, x0 = (int)x0f;
    int y1 = y0 + 1, x1 = x0 + 1;
    float w00 = (1.f-wy)*(1.f-wx), w01 = (1.f-wy)*wx;
    float w10 = wy*(1.f-wx),       w11 = wy*wx;
    if (y0 < 0 || y0 >= HH) { w00 = 0.f; w01 = 0.f; }
    if (y1 < 0 || y1 >= HH) { w10 = 0.f; w11 = 0.f; }
    if (x0 < 0 || x0 >= WW) { w00 = 0.f; w10 = 0.f; }
    if (x1 < 0 || x1 >= WW) { w01 = 0.f; w11 = 0.f; }
    int y0c = min(max(y0,0),HH-1), y1c = min(max(y1,0),HH-1);
    int x0c = min(max(x0,0),WW-1), x1c = min(max(x1,0),WW-1);
    int pbix = n << 12;
    t_off[s][0] = (pbix + y0c*WW + x0c) << 10;   // byte offset (256ch*4B per pixel)
    t_off[s][1] = (pbix + y0c*WW + x1c) << 10;
    t_off[s][2] = (pbix + y1c*WW + x0c) << 10;
    t_off[s][3] = (pbix + y1c*WW + x1c) << 10;
    t_w[s][0] = w00; t_w[s][1] = w01; t_w[s][2] = w10; t_w[s][3] = w11;
  }
  __syncthreads();

  int wid = t >> 6, lane = t & 63;
  int pxl = t >> 3, q = t & 7;               // gather role: px (0..63), channel-quad (4ch)
  const char* sbase = (const char*)src;
  const char* wpb = (const char*)wp;

  // A LDS write byte address (within one 4KB buffer), swizzled
  int abyte = pxl*64 + ((q*8) ^ ((pxl & 3) << 4));

  // frag read byte bases (within one buffer)
  int kq = lane >> 4, fr = lane & 15;
  int abr[4], bbr[2];
#pragma unroll
  for (int mi = 0; mi < 4; ++mi){
    int apx = mi*16 + fr;
    abr[mi] = apx*64 + ((kq*16) ^ ((apx & 3) << 4));
  }
#pragma unroll
  for (int ni = 0; ni < 2; ++ni){
    int o = wid*32 + ni*16 + fr;
    bbr[ni] = o*64 + ((kq*16) ^ ((o & 3) << 4));
  }

  f32x4 acc[4][2];
#pragma unroll
  for (int i = 0; i < 4; ++i)
#pragma unroll
    for (int j = 0; j < 2; ++j)
      acc[i][j] = (f32x4){0.f,0.f,0.f,0.f};

  // ---- prologue: stage step 0 into buffer 0 ----
  {
    int slot = pxl*9;                        // tap 0
    int chb = q << 4;
    int4 o4 = *(const int4*)t_off[slot];
    float4 wv = *(const float4*)t_w[slot];
    float4 ga = *(const float4*)(sbase + (size_t)(unsigned)(o4.x + chb));
    float4 gb = *(const float4*)(sbase + (size_t)(unsigned)(o4.y + chb));
    float4 gc = *(const float4*)(sbase + (size_t)(unsigned)(o4.z + chb));
    float4 gd = *(const float4*)(sbase + (size_t)(unsigned)(o4.w + chb));
    const char* bsrc = wpb + wid*2048 + lane*16;
    GLD(bsrc,        (char*)Bl + wid*2048);
    GLD(bsrc + 1024, (char*)Bl + wid*2048 + 1024);
    float v0 = wv.x*ga.x + wv.y*gb.x + wv.z*gc.x + wv.w*gd.x;
    float v1 = wv.x*ga.y + wv.y*gb.y + wv.z*gc.y + wv.w*gd.y;
    float v2 = wv.x*ga.z + wv.y*gb.z + wv.z*gc.z + wv.w*gd.z;
    float v3 = wv.x*ga.w + wv.y*gb.w + wv.z*gc.w + wv.w*gd.w;
    ushort4 st; st.x = f2bf(v0); st.y = f2bf(v1); st.z = f2bf(v2); st.w = f2bf(v3);
    *(ushort4*)((char*)Al + abyte) = st;
    __syncthreads();
  }

  for (int kt = 0; kt < 72; ++kt){
    int cur = kt & 1, nxt = cur ^ 1;
    // ---- issue next-step loads first (consumed just before next barrier) ----
    int ktn = (kt < 71) ? kt + 1 : 71;
    int slotn = pxl*9 + (ktn >> 3);
    int chb = ((ktn & 7) << 7) + (q << 4);
    int4 o4 = *(const int4*)t_off[slotn];
    float4 wv = *(const float4*)t_w[slotn];
    float4 ga = *(const float4*)(sbase + (size_t)(unsigned)(o4.x + chb));
    float4 gb = *(const float4*)(sbase + (size_t)(unsigned)(o4.y + chb));
    float4 gc = *(const float4*)(sbase + (size_t)(unsigned)(o4.z + chb));
    float4 gd = *(const float4*)(sbase + (size_t)(unsigned)(o4.w + chb));
    const char* bsrc = wpb + (size_t)ktn*16384 + wid*2048 + lane*16;
    char* bdst = (char*)Bl + nxt*16384 + wid*2048;
    GLD(bsrc,        bdst);
    GLD(bsrc + 1024, bdst + 1024);

    // ---- compute current step from buffer[cur] ----
    const char* Ac = (const char*)Al + cur*4096;
    const char* Bc = (const char*)Bl + cur*16384;
    bf16x8 av0 = *(const bf16x8*)(Ac + abr[0]);
    bf16x8 av1 = *(const bf16x8*)(Ac + abr[1]);
    bf16x8 av2 = *(const bf16x8*)(Ac + abr[2]);
    bf16x8 av3 = *(const bf16x8*)(Ac + abr[3]);
    bf16x8 bv0 = *(const bf16x8*)(Bc + bbr[0]);
    bf16x8 bv1 = *(const bf16x8*)(Bc + bbr[1]);
    acc[0][0] = __builtin_amdgcn_mfma_f32_16x16x32_bf16(av0, bv0, acc[0][0], 0, 0, 0);
    acc[0][1] = __builtin_amdgcn_mfma_f32_16x16x32_bf16(av0, bv1, acc[0][1], 0, 0, 0);
    acc[1][0] = __builtin_amdgcn_mfma_f32_16x16x32_bf16(av1, bv0, acc[1][0], 0, 0, 0);
    acc[1][1] = __builtin_amdgcn_mfma_f32_16x16x32_bf16(av1, bv1, acc[1][1], 0, 0, 0);
    acc[2][0] = __builtin_amdgcn_mfma_f32_16x16x32_bf16(av2, bv0, acc[2][0], 0, 0, 0);
    acc[2][1] = __builtin_amdgcn_mfma_f32_16x16x32_bf16(av2, bv1, acc[2][1], 0, 0, 0);
    acc[3][0] = __builtin_amdgcn_mfma_f32_16x16x32_bf16(av3, bv0, acc[3][0], 0, 0, 0);
    acc[3][1] = __builtin_amdgcn_mfma_f32_16x16x32_bf16(av3, bv1, acc[3][1], 0, 0, 0);

    // ---- convert arrived gather -> A[nxt] ----
    float v0 = wv.x*ga.x + wv.y*gb.x + wv.z*gc.x + wv.w*gd.x;
    float v1 = wv.x*ga.y + wv.y*gb.y + wv.z*gc.y + wv.w*gd.y;
    float v2 = wv.x*ga.z + wv.y*gb.z + wv.z*gc.z + wv.w*gd.z;
    float v3 = wv.x*ga.w + wv.y*gb.w + wv.z*gc.w + wv.w*gd.w;
    ushort4 st; st.x = f2bf(v0); st.y = f2bf(v1); st.z = f2bf(v2); st.w = f2bf(v3);
    *(ushort4*)((char*)Al + nxt*4096 + abyte) = st;
    __syncthreads();   // one barrier per step: drains A ds_write + B loads
  }

  // ---- epilogue: direct write to gout ----
#pragma unroll
  for (int mi = 0; mi < 4; ++mi)
#pragma unroll
    for (int ni = 0; ni < 2; ++ni){
      int rr = pbase + mi*16 + (lane>>4)*4;
      int cc = wid*32 + ni*16 + fr;
#pragma unroll
      for (int r = 0; r < 4; ++r)
        gout[(size_t)(rr + r)*CCH + cc] = acc[mi][ni][r];
    }
}

// ---------------- BN stats: per-channel sum & sumsq ----------------
__global__ __launch_bounds__(256) void k_bn_stats(const float* __restrict__ v,
                                                  float* __restrict__ stats){
  int t = threadIdx.x;
  int p0 = blockIdx.x * 128;
  float s = 0.f, ss = 0.f;
  for (int i = 0; i < 128; ++i){
    float x = v[(size_t)(p0 + i)*CCH + t];
    s += x; ss += x*x;
  }
  atomicAdd(&stats[t], s);
  atomicAdd(&stats[CCH + t], ss);
}

// ---------------- BN apply + ReLU (channels-last in/out) ----------------
__global__ __launch_bounds__(256) void k_bn_apply(const float* __restrict__ v,
    const float* __restrict__ stats, const float* __restrict__ g,
    const float* __restrict__ bb, float* __restrict__ y){
  const float inv = 1.f/16384.f;
  for (size_t i = (size_t)blockIdx.x*256 + threadIdx.x; i < (size_t)NPIX*CCH;
       i += (size_t)gridDim.x*256){
    int c = (int)(i & 255);
    float mean = stats[c]*inv;
    float var  = stats[CCH + c]*inv - mean*mean;
    float sc = g[c]*rsqrtf(var + EPSB);
    float sh = bb[c] - mean*sc;
    float val = fmaf(v[i], sc, sh);
    y[i] = val > 0.f ? val : 0.f;
  }
}

// ---------------- final: BN2 + residual + ReLU, transpose to NCHW ----------------
__global__ __launch_bounds__(256) void k_final(const float* __restrict__ v,
    const float* __restrict__ stats, const float* __restrict__ g,
    const float* __restrict__ bb, const float* __restrict__ x,
    float* __restrict__ out){
  __shared__ float tile[64][65];
  int hw0 = blockIdx.x * 64;
  int o0  = blockIdx.y * 64;
  int n   = blockIdx.z;
  int t = threadIdx.x;
  int col = t & 63, rb = t >> 6;
  const float inv = 1.f/16384.f;
#pragma unroll
  for (int r = 0; r < 16; ++r){
    int pl = rb + r*4;
    tile[pl][col] = v[(size_t)(n*HWSZ + hw0 + pl)*CCH + o0 + col];
  }
  __syncthreads();
#pragma unroll
  for (int r = 0; r < 16; ++r){
    int ol = rb + r*4;
    int o = o0 + ol;
    float mean = stats[o]*inv;
    float var  = stats[CCH + o]*inv - mean*mean;
    float sc = g[o]*rsqrtf(var + EPSB);
    float sh = bb[o] - mean*sc;
    size_t gi = (size_t)(n*CCH + o)*HWSZ + hw0 + col;
    float val = fmaf(tile[col][ol], sc, sh) + x[gi];
    out[gi] = val > 0.f ? val : 0.f;
  }
}

extern "C" void kernel_launch(void* const* d_in, const int* in_sizes, int n_in,
                              void* d_out, int out_size, void* d_ws, size_t ws_size,
                              hipStream_t stream){
  const float* x     = (const float*)d_in[0];
  const float* tm1_w = (const float*)d_in[1];
  const float* tm1_b = (const float*)d_in[2];
  const float* tr1_w = (const float*)d_in[3];
  const float* tr1_b = (const float*)d_in[4];
  const float* dcn1_w= (const float*)d_in[5];
  const float* bn1_g = (const float*)d_in[6];
  const float* bn1_b = (const float*)d_in[7];
  const float* tm2_w = (const float*)d_in[8];
  const float* tm2_b = (const float*)d_in[9];
  const float* tr2_w = (const float*)d_in[10];
  const float* tr2_b = (const float*)d_in[11];
  const float* dcn2_w= (const float*)d_in[12];
  const float* bn2_g = (const float*)d_in[13];
  const float* bn2_b = (const float*)d_in[14];
  float* out = (float*)d_out;

  char* ws = (char*)d_ws;
  size_t cursor = 0;
  auto alloc = [&](size_t bytes)->char*{
    char* p = ws + cursor; cursor += (bytes + 255) & ~(size_t)255; return p;
  };
  float* xT    = (float*)alloc((size_t)NPIX*CCH*4);
  float* ybuf  = (float*)alloc((size_t)NPIX*CCH*4);
  float* gout  = (float*)alloc((size_t)NPIX*CCH*4);
  float* offb  = (float*)alloc((size_t)NPIX*9*2*4);
  float* woff1 = (float*)alloc(9*6*CCH*4);
  float* woff2 = (float*)alloc(9*6*CCH*4);
  __hip_bfloat16* wg1 = (__hip_bfloat16*)alloc((size_t)CCH*CK*2);
  __hip_bfloat16* wg2 = (__hip_bfloat16*)alloc((size_t)CCH*CK*2);
  float* stats = (float*)alloc(1024*4);

  hipMemsetAsync(stats, 0, 1024*4, stream);
  k_transpose_in<<<dim3(64,4,4),256,0,stream>>>(x, xT);
  k_woff_perm<<<54,256,0,stream>>>(tm1_w, tr1_w, woff1);
  k_woff_perm<<<54,256,0,stream>>>(tm2_w, tr2_w, woff2);
  k_wgemm_perm<<<2304,256,0,stream>>>(dcn1_w, wg1);
  k_wgemm_perm<<<2304,256,0,stream>>>(dcn2_w, wg2);

  // ---- layer 1 ----
  k_offsets<<<512,256,0,stream>>>(xT, woff1, tm1_b, tr1_b, offb);
  k_dcn<<<256,512,0,stream>>>(xT, offb, wg1, gout);
  k_bn_stats<<<128,256,0,stream>>>(gout, stats);
  k_bn_apply<<<2048,256,0,stream>>>(gout, stats, bn1_g, bn1_b, ybuf);

  // ---- layer 2 ----
  k_offsets<<<512,256,0,stream>>>(ybuf, woff2, tm2_b, tr2_b, offb);
  k_dcn<<<256,512,0,stream>>>(ybuf, offb, wg2, gout);
  k_bn_stats<<<128,256,0,stream>>>(gout, stats + 512);
  k_final<<<dim3(64,4,4),256,0,stream>>>(gout, stats + 512, bn2_g, bn2_b, x, out);
}

// Round 7
// 206.137 us; speedup vs baseline: 1.8981x; 1.0637x over previous
//
#include <hip/hip_runtime.h>
#include <hip/hip_bf16.h>

#define HH 64
#define WW 64
#define HWSZ 4096
#define NBATCH 4
#define CCH 256
#define NPIX 16384   // NBATCH*HWSZ
#define CK 2304      // 9*256
#define EPSB 1e-5f

typedef __attribute__((ext_vector_type(8))) short bf16x8;
typedef __attribute__((ext_vector_type(4))) float f32x4;

static __device__ __forceinline__ unsigned short f2bf(float f){
  __hip_bfloat16 h = __float2bfloat16(f);
  return *(unsigned short*)&h;
}

#if __has_builtin(__builtin_amdgcn_global_load_lds)
#define GLD(S,D) __builtin_amdgcn_global_load_lds((const __attribute__((address_space(1))) void*)(S), \
                                                  (__attribute__((address_space(3))) void*)(D), 16, 0, 0)
#else
#define GLD(S,D) (*(bf16x8*)((char*)(D) + lane*16) = *(const bf16x8*)(S))
#endif

// ---------------- transpose x (N,C,H,W) -> xT (N,HW,C) ----------------
__global__ __launch_bounds__(256) void k_transpose_in(const float* __restrict__ x,
                                                      float* __restrict__ xT){
  __shared__ float tile[64][65];
  int hw0 = blockIdx.x * 64;
  int c0  = blockIdx.y * 64;
  int n   = blockIdx.z;
  int t = threadIdx.x;
  int col = t & 63, rb = t >> 6;
#pragma unroll
  for (int r = 0; r < 16; ++r){
    int cl = rb + r*4;
    tile[cl][col] = x[(size_t)(n*CCH + c0 + cl)*HWSZ + hw0 + col];
  }
  __syncthreads();
#pragma unroll
  for (int r = 0; r < 16; ++r){
    int hwl = rb + r*4;
    xT[(size_t)(n*HWSZ + hw0 + hwl)*CCH + c0 + col] = tile[col][hwl];
  }
}

// ---------------- permute offset-conv weights to [k][j][c] (c contiguous) ----------------
__global__ void k_woff_perm(const float* __restrict__ tmw, const float* __restrict__ trw,
                            float* __restrict__ woff){
  int idx = blockIdx.x*256 + threadIdx.x;   // 9*6*256 = 13824
  if (idx >= 9*6*CCH) return;
  int k = idx / (6*CCH); int rem = idx % (6*CCH); int j = rem >> 8; int c = rem & 255;
  float v = (j < 4) ? tmw[(size_t)(j*CCH + c)*9 + k]
                    : trw[(size_t)((j-4)*CCH + c)*9 + k];
  woff[idx] = v;
}

// ---------------- pack dcn weights (Co,C,3,3) -> bf16 blocks [tap*8+cb][o][32ch],
// with LDS XOR-swizzle baked in: logical elem m stored at m ^ (8*(o&3)) ----------------
__global__ void k_wgemm_perm(const float* __restrict__ w, __hip_bfloat16* __restrict__ wp){
  int idx = blockIdx.x*256 + threadIdx.x;    // 589824 total
  if (idx >= CCH*CK) return;
  int blk = idx >> 13;        // tap*8 + cb  (72 blocks of 8192 elems)
  int e   = idx & 8191;
  int o   = e >> 5;
  int el  = e & 31;
  int tap = blk >> 3, cb = blk & 7;
  int c   = cb*32 + (el ^ ((o & 3) << 3));
  wp[idx] = __float2bfloat16(w[(size_t)o*CK + c*9 + tap]);
}

// ---------------- offset generation: conv3x3(6ch) + make_offset, no LDS ----------------
__global__ __launch_bounds__(256) void k_offsets(const float* __restrict__ src,
    const float* __restrict__ wofft, const float* __restrict__ tmb,
    const float* __restrict__ trb, float* __restrict__ off){
  int t = threadIdx.x;
  int wid = t >> 6, lane = t & 63;
  int pbase = blockIdx.x*32 + wid*8;          // 512 blocks * 4 waves * 8 pixels
  int n = pbase >> 12; int hw = pbase & 4095; int h = hw >> 6; int w0 = hw & 63;
  const float* base = src + (size_t)n*HWSZ*CCH + lane*4;

  float acc[8][6];
#pragma unroll
  for (int pi = 0; pi < 8; ++pi)
#pragma unroll
    for (int j = 0; j < 6; ++j) acc[pi][j] = 0.f;

  for (int k = 0; k < 9; ++k){
    int ky = k/3 - 1, kx = k%3 - 1;
    int yy = h + ky;
    if (yy < 0 || yy >= HH) continue;
    float4 wv[6];
#pragma unroll
    for (int j = 0; j < 6; ++j)
      wv[j] = *(const float4*)(wofft + ((k*6 + j) << 8) + lane*4);
#pragma unroll
    for (int pi = 0; pi < 8; ++pi){
      int xx = w0 + pi + kx;
      if (xx < 0 || xx >= WW) continue;
      float4 s4 = *(const float4*)(base + (size_t)(yy*WW + xx)*CCH);
#pragma unroll
      for (int j = 0; j < 6; ++j)
        acc[pi][j] += s4.x*wv[j].x + s4.y*wv[j].y + s4.z*wv[j].z + s4.w*wv[j].w;
    }
  }

#pragma unroll
  for (int pi = 0; pi < 8; ++pi)
#pragma unroll
    for (int j = 0; j < 6; ++j){
      float v = acc[pi][j];
#pragma unroll
      for (int m = 32; m >= 1; m >>= 1) v += __shfl_xor(v, m);
      acc[pi][j] = v;
    }

  float b0 = tmb[0], b1 = tmb[1], b2 = tmb[2], b3 = tmb[3];
  float c0 = trb[0], c1 = trb[1];
  if (lane < 18){
    int k = lane >> 1, comp = lane & 1;
    float dy = (float)(k/3 - 1), dx = (float)(k%3 - 1);
#pragma unroll
    for (int pi = 0; pi < 8; ++pi){
      int p = pbase + pi;
      float val;
      if (comp == 0)
        val = (acc[pi][0] + b0)*dy + (acc[pi][1] + b1)*dx - dy + acc[pi][4] + c0;
      else
        val = (acc[pi][2] + b2)*dy + (acc[pi][3] + b3)*dx - dx + acc[pi][5] + c1;
      off[((size_t)p*9 + k)*2 + comp] = val;
    }
  }
}

// ---------------- fused deform-im2col + GEMM, counted-vmcnt pipeline ----------------
// Grid 256 (XCD-swizzled), 512 thr. Tile 64px x 256och, K = 72 steps of 32ch
// (tap-major). B: 4 LDS buffers, global_load_lds issued at distance 2. A: gathers
// held in 2 register sets (distance 2), converted + ds_written one step ahead into
// 2 LDS buffers. ONE raw s_barrier per step with lgkmcnt(0) only — vmcnt is never
// drained to 0 in the loop (loads stay in flight across barriers).
struct Gset { float4 a, b, c, d; };

__global__ __launch_bounds__(512) void k_dcn(const float* __restrict__ src,
    const float* __restrict__ off, const __hip_bfloat16* __restrict__ wp,
    float* __restrict__ gout){
  __shared__ __hip_bfloat16 Al[2*64*32];     // 2 x 4KB
  __shared__ __hip_bfloat16 Bl[4*256*32];    // 4 x 16KB
  __shared__ __align__(16) int   t_off[576][4];
  __shared__ __align__(16) float t_w[576][4];

  int t = threadIdx.x;
  int bid = blockIdx.x;
  int tile = (bid & 7)*32 + (bid >> 3);      // XCD-bijective: 32 contiguous tiles/XCD
  int pbase = tile * 64;

  // ---- setup: 576 slots = 64 px x 9 taps ----
  for (int s = t; s < 576; s += 512){
    int px = s / 9, k = s - px*9;
    int p = pbase + px;
    int n = p >> 12; int hw = p & 4095; int h = hw >> 6; int w = hw & 63;
    float2 of = *(const float2*)(off + ((size_t)p*9 + k)*2);
    float py = (float)(h + k/3 - 1) + of.x;
    float px_ = (float)(w + (k - (k/3)*3) - 1) + of.y;
    float y0f = floorf(py), x0f = floorf(px_);
    float wy = py - y0f, wx = px_ - x0f;
    int y0 = (int)y0f, x0 = (int)x0f;
    int y1 = y0 + 1, x1 = x0 + 1;
    float w00 = (1.f-wy)*(1.f-wx), w01 = (1.f-wy)*wx;
    float w10 = wy*(1.f-wx),       w11 = wy*wx;
    if (y0 < 0 || y0 >= HH) { w00 = 0.f; w01 = 0.f; }
    if (y1 < 0 || y1 >= HH) { w10 = 0.f; w11 = 0.f; }
    if (x0 < 0 || x0 >= WW) { w00 = 0.f; w10 = 0.f; }
    if (x1 < 0 || x1 >= WW) { w01 = 0.f; w11 = 0.f; }
    int y0c = min(max(y0,0),HH-1), y1c = min(max(y1,0),HH-1);
    int x0c = min(max(x0,0),WW-1), x1c = min(max(x1,0),WW-1);
    int pbix = n << 12;
    t_off[s][0] = (pbix + y0c*WW + x0c) << 10;   // byte offset (256ch*4B per pixel)
    t_off[s][1] = (pbix + y0c*WW + x1c) << 10;
    t_off[s][2] = (pbix + y1c*WW + x0c) << 10;
    t_off[s][3] = (pbix + y1c*WW + x1c) << 10;
    t_w[s][0] = w00; t_w[s][1] = w01; t_w[s][2] = w10; t_w[s][3] = w11;
  }
  __syncthreads();

  int wid = t >> 6, lane = t & 63;
  int pxl = t >> 3, q = t & 7;               // gather role: px (0..63), channel-quad (4ch)
  const char* sbase = (const char*)src;
  const char* wpb = (const char*)wp;

  // A LDS write byte address (within one 4KB buffer), swizzled
  int abyte = pxl*64 + ((q*8) ^ ((pxl & 3) << 4));

  // frag read byte bases (within one buffer)
  int kq = lane >> 4, fr = lane & 15;
  int abr0, abr1, abr2, abr3, bbr0, bbr1;
  {
    int apx0 = 0*16 + fr;  abr0 = apx0*64 + ((kq*16) ^ ((apx0 & 3) << 4));
    int apx1 = 1*16 + fr;  abr1 = apx1*64 + ((kq*16) ^ ((apx1 & 3) << 4));
    int apx2 = 2*16 + fr;  abr2 = apx2*64 + ((kq*16) ^ ((apx2 & 3) << 4));
    int apx3 = 3*16 + fr;  abr3 = apx3*64 + ((kq*16) ^ ((apx3 & 3) << 4));
    int o0 = wid*32 + 0*16 + fr;  bbr0 = o0*64 + ((kq*16) ^ ((o0 & 3) << 4));
    int o1 = wid*32 + 1*16 + fr;  bbr1 = o1*64 + ((kq*16) ^ ((o1 & 3) << 4));
  }

  f32x4 acc[4][2];
#pragma unroll
  for (int i = 0; i < 4; ++i)
#pragma unroll
    for (int j = 0; j < 2; ++j)
      acc[i][j] = (f32x4){0.f,0.f,0.f,0.f};

  Gset gA, gB;

  auto issue_gather = [&](int ktn, Gset& g){
    int slot = pxl*9 + (ktn >> 3);
    int chb = ((ktn & 7) << 7) + (q << 4);
    int4 o4 = *(const int4*)t_off[slot];
    g.a = *(const float4*)(sbase + (size_t)(unsigned)(o4.x + chb));
    g.b = *(const float4*)(sbase + (size_t)(unsigned)(o4.y + chb));
    g.c = *(const float4*)(sbase + (size_t)(unsigned)(o4.z + chb));
    g.d = *(const float4*)(sbase + (size_t)(unsigned)(o4.w + chb));
  };
  auto convert_write = [&](int ktc, Gset& g){
    int slot = pxl*9 + (ktc >> 3);
    float4 wv = *(const float4*)t_w[slot];
    float v0 = wv.x*g.a.x + wv.y*g.b.x + wv.z*g.c.x + wv.w*g.d.x;
    float v1 = wv.x*g.a.y + wv.y*g.b.y + wv.z*g.c.y + wv.w*g.d.y;
    float v2 = wv.x*g.a.z + wv.y*g.b.z + wv.z*g.c.z + wv.w*g.d.z;
    float v3 = wv.x*g.a.w + wv.y*g.b.w + wv.z*g.c.w + wv.w*g.d.w;
    ushort4 st; st.x = f2bf(v0); st.y = f2bf(v1); st.z = f2bf(v2); st.w = f2bf(v3);
    *(ushort4*)((char*)Al + (ktc & 1)*4096 + abyte) = st;
  };
  auto issue_B = [&](int ktb){
    const char* bsrc = wpb + (size_t)ktb*16384 + wid*2048 + lane*16;
    char* bdst = (char*)Bl + (ktb & 3)*16384 + wid*2048;
    GLD(bsrc,        bdst);
    GLD(bsrc + 1024, bdst + 1024);
  };

  // ---- prologue: B_0,B_1 in flight; g_0,g_1 in flight; A_0 written ----
  issue_B(0);
  issue_B(1);
  asm volatile("" ::: "memory");
  issue_gather(0, gA);
  issue_gather(1, gB);
  convert_write(0, gA);                       // auto-waits g_0 (retires B_0,B_1 too)
  asm volatile("s_waitcnt lgkmcnt(0)" ::: "memory");
  __builtin_amdgcn_s_barrier();

  auto body = [&](int kt, Gset& gIss, Gset& gCnv){
    // B_kt guaranteed resident (retired by earlier waits); guard for tails:
    asm volatile("s_waitcnt vmcnt(6)" ::: "memory");
    __builtin_amdgcn_sched_barrier(0);
    const char* Ac = (const char*)Al + (kt & 1)*4096;
    const char* Bc = (const char*)Bl + (kt & 3)*16384;
    bf16x8 av0 = *(const bf16x8*)(Ac + abr0);
    bf16x8 av1 = *(const bf16x8*)(Ac + abr1);
    bf16x8 av2 = *(const bf16x8*)(Ac + abr2);
    bf16x8 av3 = *(const bf16x8*)(Ac + abr3);
    bf16x8 bv0 = *(const bf16x8*)(Bc + bbr0);
    bf16x8 bv1 = *(const bf16x8*)(Bc + bbr1);
    if (kt <= 69) issue_B(kt + 2);
    asm volatile("" ::: "memory");            // pin: B GLDs issue before gathers
    if (kt <= 69) issue_gather(kt + 2, gIss);
    acc[0][0] = __builtin_amdgcn_mfma_f32_16x16x32_bf16(av0, bv0, acc[0][0], 0, 0, 0);
    acc[0][1] = __builtin_amdgcn_mfma_f32_16x16x32_bf16(av0, bv1, acc[0][1], 0, 0, 0);
    acc[1][0] = __builtin_amdgcn_mfma_f32_16x16x32_bf16(av1, bv0, acc[1][0], 0, 0, 0);
    acc[1][1] = __builtin_amdgcn_mfma_f32_16x16x32_bf16(av1, bv1, acc[1][1], 0, 0, 0);
    acc[2][0] = __builtin_amdgcn_mfma_f32_16x16x32_bf16(av2, bv0, acc[2][0], 0, 0, 0);
    acc[2][1] = __builtin_amdgcn_mfma_f32_16x16x32_bf16(av2, bv1, acc[2][1], 0, 0, 0);
    acc[3][0] = __builtin_amdgcn_mfma_f32_16x16x32_bf16(av3, bv0, acc[3][0], 0, 0, 0);
    acc[3][1] = __builtin_amdgcn_mfma_f32_16x16x32_bf16(av3, bv1, acc[3][1], 0, 0, 0);
    if (kt <= 70) convert_write(kt + 1, gCnv); // auto-waits gCnv's loads
    asm volatile("s_waitcnt lgkmcnt(0)" ::: "memory");
    __builtin_amdgcn_s_barrier();
  };

  for (int kk = 0; kk < 72; kk += 2){
    body(kk + 0, gA, gB);   // issue g_{kk+2} into gA, convert g_{kk+1} from gB
    body(kk + 1, gB, gA);   // issue g_{kk+3} into gB, convert g_{kk+2} from gA
  }

  // ---- epilogue: direct write to gout ----
#pragma unroll
  for (int mi = 0; mi < 4; ++mi)
#pragma unroll
    for (int ni = 0; ni < 2; ++ni){
      int rr = pbase + mi*16 + (lane>>4)*4;
      int cc = wid*32 + ni*16 + fr;
#pragma unroll
      for (int r = 0; r < 4; ++r)
        gout[(size_t)(rr + r)*CCH + cc] = acc[mi][ni][r];
    }
}

// ---------------- BN stats: per-channel sum & sumsq ----------------
__global__ __launch_bounds__(256) void k_bn_stats(const float* __restrict__ v,
                                                  float* __restrict__ stats){
  int t = threadIdx.x;
  int p0 = blockIdx.x * 128;
  float s = 0.f, ss = 0.f;
  for (int i = 0; i < 128; ++i){
    float x = v[(size_t)(p0 + i)*CCH + t];
    s += x; ss += x*x;
  }
  atomicAdd(&stats[t], s);
  atomicAdd(&stats[CCH + t], ss);
}

// ---------------- BN apply + ReLU (channels-last in/out) ----------------
__global__ __launch_bounds__(256) void k_bn_apply(const float* __restrict__ v,
    const float* __restrict__ stats, const float* __restrict__ g,
    const float* __restrict__ bb, float* __restrict__ y){
  const float inv = 1.f/16384.f;
  for (size_t i = (size_t)blockIdx.x*256 + threadIdx.x; i < (size_t)NPIX*CCH;
       i += (size_t)gridDim.x*256){
    int c = (int)(i & 255);
    float mean = stats[c]*inv;
    float var  = stats[CCH + c]*inv - mean*mean;
    float sc = g[c]*rsqrtf(var + EPSB);
    float sh = bb[c] - mean*sc;
    float val = fmaf(v[i], sc, sh);
    y[i] = val > 0.f ? val : 0.f;
  }
}

// ---------------- final: BN2 + residual + ReLU, transpose to NCHW ----------------
__global__ __launch_bounds__(256) void k_final(const float* __restrict__ v,
    const float* __restrict__ stats, const float* __restrict__ g,
    const float* __restrict__ bb, const float* __restrict__ x,
    float* __restrict__ out){
  __shared__ float tile[64][65];
  int hw0 = blockIdx.x * 64;
  int o0  = blockIdx.y * 64;
  int n   = blockIdx.z;
  int t = threadIdx.x;
  int col = t & 63, rb = t >> 6;
  const float inv = 1.f/16384.f;
#pragma unroll
  for (int r = 0; r < 16; ++r){
    int pl = rb + r*4;
    tile[pl][col] = v[(size_t)(n*HWSZ + hw0 + pl)*CCH + o0 + col];
  }
  __syncthreads();
#pragma unroll
  for (int r = 0; r < 16; ++r){
    int ol = rb + r*4;
    int o = o0 + ol;
    float mean = stats[o]*inv;
    float var  = stats[CCH + o]*inv - mean*mean;
    float sc = g[o]*rsqrtf(var + EPSB);
    float sh = bb[o] - mean*sc;
    size_t gi = (size_t)(n*CCH + o)*HWSZ + hw0 + col;
    float val = fmaf(tile[col][ol], sc, sh) + x[gi];
    out[gi] = val > 0.f ? val : 0.f;
  }
}

extern "C" void kernel_launch(void* const* d_in, const int* in_sizes, int n_in,
                              void* d_out, int out_size, void* d_ws, size_t ws_size,
                              hipStream_t stream){
  const float* x     = (const float*)d_in[0];
  const float* tm1_w = (const float*)d_in[1];
  const float* tm1_b = (const float*)d_in[2];
  const float* tr1_w = (const float*)d_in[3];
  const float* tr1_b = (const float*)d_in[4];
  const float* dcn1_w= (const float*)d_in[5];
  const float* bn1_g = (const float*)d_in[6];
  const float* bn1_b = (const float*)d_in[7];
  const float* tm2_w = (const float*)d_in[8];
  const float* tm2_b = (const float*)d_in[9];
  const float* tr2_w = (const float*)d_in[10];
  const float* tr2_b = (const float*)d_in[11];
  const float* dcn2_w= (const float*)d_in[12];
  const float* bn2_g = (const float*)d_in[13];
  const float* bn2_b = (const float*)d_in[14];
  float* out = (float*)d_out;

  char* ws = (char*)d_ws;
  size_t cursor = 0;
  auto alloc = [&](size_t bytes)->char*{
    char* p = ws + cursor; cursor += (bytes + 255) & ~(size_t)255; return p;
  };
  float* xT    = (float*)alloc((size_t)NPIX*CCH*4);
  float* ybuf  = (float*)alloc((size_t)NPIX*CCH*4);
  float* gout  = (float*)alloc((size_t)NPIX*CCH*4);
  float* offb  = (float*)alloc((size_t)NPIX*9*2*4);
  float* woff1 = (float*)alloc(9*6*CCH*4);
  float* woff2 = (float*)alloc(9*6*CCH*4);
  __hip_bfloat16* wg1 = (__hip_bfloat16*)alloc((size_t)CCH*CK*2);
  __hip_bfloat16* wg2 = (__hip_bfloat16*)alloc((size_t)CCH*CK*2);
  float* stats = (float*)alloc(1024*4);

  hipMemsetAsync(stats, 0, 1024*4, stream);
  k_transpose_in<<<dim3(64,4,4),256,0,stream>>>(x, xT);
  k_woff_perm<<<54,256,0,stream>>>(tm1_w, tr1_w, woff1);
  k_woff_perm<<<54,256,0,stream>>>(tm2_w, tr2_w, woff2);
  k_wgemm_perm<<<2304,256,0,stream>>>(dcn1_w, wg1);
  k_wgemm_perm<<<2304,256,0,stream>>>(dcn2_w, wg2);

  // ---- layer 1 ----
  k_offsets<<<512,256,0,stream>>>(xT, woff1, tm1_b, tr1_b, offb);
  k_dcn<<<256,512,0,stream>>>(xT, offb, wg1, gout);
  k_bn_stats<<<128,256,0,stream>>>(gout, stats);
  k_bn_apply<<<2048,256,0,stream>>>(gout, stats, bn1_g, bn1_b, ybuf);

  // ---- layer 2 ----
  k_offsets<<<512,256,0,stream>>>(ybuf, woff2, tm2_b, tr2_b, offb);
  k_dcn<<<256,512,0,stream>>>(ybuf, offb, wg2, gout);
  k_bn_stats<<<128,256,0,stream>>>(gout, stats + 512);
  k_final<<<dim3(64,4,4),256,0,stream>>>(gout, stats + 512, bn2_g, bn2_b, x, out);
}

// Round 8
// 201.899 us; speedup vs baseline: 1.9379x; 1.0210x over previous
//
#include <hip/hip_runtime.h>
#include <hip/hip_bf16.h>

#define HH 64
#define WW 64
#define HWSZ 4096
#define NBATCH 4
#define CCH 256
#define NPIX 16384   // NBATCH*HWSZ
#define CK 2304      // 9*256
#define EPSB 1e-5f

typedef __attribute__((ext_vector_type(8))) short bf16x8;
typedef __attribute__((ext_vector_type(4))) float f32x4;

static __device__ __forceinline__ unsigned short f2bf(float f){
  __hip_bfloat16 h = __float2bfloat16(f);
  return *(unsigned short*)&h;
}

#if __has_builtin(__builtin_amdgcn_global_load_lds)
#define GLD(S,D) __builtin_amdgcn_global_load_lds((const __attribute__((address_space(1))) void*)(S), \
                                                  (__attribute__((address_space(3))) void*)(D), 16, 0, 0)
#else
#define GLD(S,D) (*(bf16x8*)((char*)(D) + (threadIdx.x & 63)*16) = *(const bf16x8*)(S))
#endif

// ---------------- transpose x (N,C,H,W) -> xT (N,HW,C) ----------------
__global__ __launch_bounds__(256) void k_transpose_in(const float* __restrict__ x,
                                                      float* __restrict__ xT){
  __shared__ float tile[64][65];
  int hw0 = blockIdx.x * 64;
  int c0  = blockIdx.y * 64;
  int n   = blockIdx.z;
  int t = threadIdx.x;
  int col = t & 63, rb = t >> 6;
#pragma unroll
  for (int r = 0; r < 16; ++r){
    int cl = rb + r*4;
    tile[cl][col] = x[(size_t)(n*CCH + c0 + cl)*HWSZ + hw0 + col];
  }
  __syncthreads();
#pragma unroll
  for (int r = 0; r < 16; ++r){
    int hwl = rb + r*4;
    xT[(size_t)(n*HWSZ + hw0 + hwl)*CCH + c0 + col] = tile[col][hwl];
  }
}

// ---------------- permute offset-conv weights to [k][j][c] (c contiguous) ----------------
__global__ void k_woff_perm(const float* __restrict__ tmw, const float* __restrict__ trw,
                            float* __restrict__ woff){
  int idx = blockIdx.x*256 + threadIdx.x;   // 9*6*256 = 13824
  if (idx >= 9*6*CCH) return;
  int k = idx / (6*CCH); int rem = idx % (6*CCH); int j = rem >> 8; int c = rem & 255;
  float v = (j < 4) ? tmw[(size_t)(j*CCH + c)*9 + k]
                    : trw[(size_t)((j-4)*CCH + c)*9 + k];
  woff[idx] = v;
}

// ---------------- pack dcn weights (Co,C,3,3) -> bf16 blocks [tap*8+cb][o][32ch],
// with LDS swizzle baked in: stored elem el holds logical c = el ^ (((o>>1)&3)<<3) ----------------
__global__ void k_wgemm_perm(const float* __restrict__ w, __hip_bfloat16* __restrict__ wp){
  int idx = blockIdx.x*256 + threadIdx.x;    // 589824 total
  if (idx >= CCH*CK) return;
  int blk = idx >> 13;        // tap*8 + cb  (72 blocks of 8192 elems)
  int e   = idx & 8191;
  int o   = e >> 5;
  int el  = e & 31;
  int tap = blk >> 3, cb = blk & 7;
  int c   = cb*32 + (el ^ (((o >> 1) & 3) << 3));
  wp[idx] = __float2bfloat16(w[(size_t)o*CK + c*9 + tap]);
}

// ---------------- offset generation: conv3x3(6ch) + make_offset, no LDS ----------------
__global__ __launch_bounds__(256) void k_offsets(const float* __restrict__ src,
    const float* __restrict__ wofft, const float* __restrict__ tmb,
    const float* __restrict__ trb, float* __restrict__ off){
  int t = threadIdx.x;
  int wid = t >> 6, lane = t & 63;
  int pbase = blockIdx.x*32 + wid*8;          // 512 blocks * 4 waves * 8 pixels
  int n = pbase >> 12; int hw = pbase & 4095; int h = hw >> 6; int w0 = hw & 63;
  const float* base = src + (size_t)n*HWSZ*CCH + lane*4;

  float acc[8][6];
#pragma unroll
  for (int pi = 0; pi < 8; ++pi)
#pragma unroll
    for (int j = 0; j < 6; ++j) acc[pi][j] = 0.f;

  for (int k = 0; k < 9; ++k){
    int ky = k/3 - 1, kx = k%3 - 1;
    int yy = h + ky;
    if (yy < 0 || yy >= HH) continue;
    float4 wv[6];
#pragma unroll
    for (int j = 0; j < 6; ++j)
      wv[j] = *(const float4*)(wofft + ((k*6 + j) << 8) + lane*4);
#pragma unroll
    for (int pi = 0; pi < 8; ++pi){
      int xx = w0 + pi + kx;
      if (xx < 0 || xx >= WW) continue;
      float4 s4 = *(const float4*)(base + (size_t)(yy*WW + xx)*CCH);
#pragma unroll
      for (int j = 0; j < 6; ++j)
        acc[pi][j] += s4.x*wv[j].x + s4.y*wv[j].y + s4.z*wv[j].z + s4.w*wv[j].w;
    }
  }

#pragma unroll
  for (int pi = 0; pi < 8; ++pi)
#pragma unroll
    for (int j = 0; j < 6; ++j){
      float v = acc[pi][j];
#pragma unroll
      for (int m = 32; m >= 1; m >>= 1) v += __shfl_xor(v, m);
      acc[pi][j] = v;
    }

  float b0 = tmb[0], b1 = tmb[1], b2 = tmb[2], b3 = tmb[3];
  float c0 = trb[0], c1 = trb[1];
  if (lane < 18){
    int k = lane >> 1, comp = lane & 1;
    float dy = (float)(k/3 - 1), dx = (float)(k%3 - 1);
#pragma unroll
    for (int pi = 0; pi < 8; ++pi){
      int p = pbase + pi;
      float val;
      if (comp == 0)
        val = (acc[pi][0] + b0)*dy + (acc[pi][1] + b1)*dx - dy + acc[pi][4] + c0;
      else
        val = (acc[pi][2] + b2)*dy + (acc[pi][3] + b3)*dx - dx + acc[pi][5] + c1;
      off[((size_t)p*9 + k)*2 + comp] = val;
    }
  }
}

// ---------------- fused deform-im2col + GEMM ----------------
// Grid 512 (XCD-bijective), 256 thr (4 waves). Tile 32px x 256och, K = 72 steps of
// 32ch (tap-major). 2 blocks co-resident per CU (LDS 77KB) -> independent barrier
// groups overlap. B: 4 LDS bufs, GLD at distance 2. A: gathers in 2 register sets
// (distance 2), converted+ds_written one step ahead into 2 bufs. One s_barrier +
// lgkmcnt(0) per step; vmcnt never drained in-loop. LDS chunk swizzle
// stored = chunk ^ ((row>>1)&3) -> fragment reads are 2-way (free).
struct Gset { float4 a, b, c, d; };

__global__ __launch_bounds__(256) void k_dcn(const float* __restrict__ src,
    const float* __restrict__ off, const __hip_bfloat16* __restrict__ wp,
    float* __restrict__ gout){
  __shared__ __hip_bfloat16 Al[2*32*32];     // 2 x 2KB
  __shared__ __hip_bfloat16 Bl[4*256*32];    // 4 x 16KB
  __shared__ __align__(16) int   t_off[288][4];
  __shared__ __align__(16) float t_w[288][4];

  int t = threadIdx.x;
  int bid = blockIdx.x;
  int tile = (bid & 7)*64 + (bid >> 3);      // XCD-bijective over 512
  int pbase = tile * 32;

  // ---- setup: 288 slots = 32 px x 9 taps ----
  for (int s = t; s < 288; s += 256){
    int px = s / 9, k = s - px*9;
    int p = pbase + px;
    int n = p >> 12; int hw = p & 4095; int h = hw >> 6; int w = hw & 63;
    float2 of = *(const float2*)(off + ((size_t)p*9 + k)*2);
    float py = (float)(h + k/3 - 1) + of.x;
    float px_ = (float)(w + (k - (k/3)*3) - 1) + of.y;
    float y0f = floorf(py), x0f = floorf(px_);
    float wy = py - y0f, wx = px_ - x0f;
    int y0 = (int)y0f, x0 = (int)x0f;
    int y1 = y0 + 1, x1 = x0 + 1;
    float w00 = (1.f-wy)*(1.f-wx), w01 = (1.f-wy)*wx;
    float w10 = wy*(1.f-wx),       w11 = wy*wx;
    if (y0 < 0 || y0 >= HH) { w00 = 0.f; w01 = 0.f; }
    if (y1 < 0 || y1 >= HH) { w10 = 0.f; w11 = 0.f; }
    if (x0 < 0 || x0 >= WW) { w00 = 0.f; w10 = 0.f; }
    if (x1 < 0 || x1 >= WW) { w01 = 0.f; w11 = 0.f; }
    int y0c = min(max(y0,0),HH-1), y1c = min(max(y1,0),HH-1);
    int x0c = min(max(x0,0),WW-1), x1c = min(max(x1,0),WW-1);
    int pbix = n << 12;
    t_off[s][0] = (pbix + y0c*WW + x0c) << 10;   // byte offset (256ch*4B per pixel)
    t_off[s][1] = (pbix + y0c*WW + x1c) << 10;
    t_off[s][2] = (pbix + y1c*WW + x0c) << 10;
    t_off[s][3] = (pbix + y1c*WW + x1c) << 10;
    t_w[s][0] = w00; t_w[s][1] = w01; t_w[s][2] = w10; t_w[s][3] = w11;
  }
  __syncthreads();

  int wid = t >> 6, lane = t & 63;
  int pxl = t >> 3, q = t & 7;               // gather role: px (0..31), channel-quad (4ch)
  const char* sbase = (const char*)src;
  const char* wpb = (const char*)wp;

  // A LDS write byte address (within one 2KB buffer): logical chunk q>>1, swizzled
  int abyte = pxl*64 + (((q >> 1) ^ ((pxl >> 1) & 3)) << 4) + (q & 1)*8;

  // frag read byte bases (within one buffer)
  int kq = lane >> 4, fr = lane & 15;
  int abr0, abr1, bbr0, bbr1, bbr2, bbr3;
  {
    int a0 = 0*16 + fr;  abr0 = a0*64 + ((kq ^ ((a0 >> 1) & 3)) << 4);
    int a1 = 1*16 + fr;  abr1 = a1*64 + ((kq ^ ((a1 >> 1) & 3)) << 4);
    int o0 = wid*64 + 0*16 + fr;  bbr0 = o0*64 + ((kq ^ ((o0 >> 1) & 3)) << 4);
    int o1 = wid*64 + 1*16 + fr;  bbr1 = o1*64 + ((kq ^ ((o1 >> 1) & 3)) << 4);
    int o2 = wid*64 + 2*16 + fr;  bbr2 = o2*64 + ((kq ^ ((o2 >> 1) & 3)) << 4);
    int o3 = wid*64 + 3*16 + fr;  bbr3 = o3*64 + ((kq ^ ((o3 >> 1) & 3)) << 4);
  }

  f32x4 acc[2][4];
#pragma unroll
  for (int i = 0; i < 2; ++i)
#pragma unroll
    for (int j = 0; j < 4; ++j)
      acc[i][j] = (f32x4){0.f,0.f,0.f,0.f};

  Gset gA, gB;

  auto issue_gather = [&](int ktn, Gset& g){
    int slot = pxl*9 + (ktn >> 3);
    int chb = ((ktn & 7) << 7) + (q << 4);
    int4 o4 = *(const int4*)t_off[slot];
    g.a = *(const float4*)(sbase + (size_t)(unsigned)(o4.x + chb));
    g.b = *(const float4*)(sbase + (size_t)(unsigned)(o4.y + chb));
    g.c = *(const float4*)(sbase + (size_t)(unsigned)(o4.z + chb));
    g.d = *(const float4*)(sbase + (size_t)(unsigned)(o4.w + chb));
  };
  auto convert_write = [&](int ktc, Gset& g){
    int slot = pxl*9 + (ktc >> 3);
    float4 wv = *(const float4*)t_w[slot];
    float v0 = wv.x*g.a.x + wv.y*g.b.x + wv.z*g.c.x + wv.w*g.d.x;
    float v1 = wv.x*g.a.y + wv.y*g.b.y + wv.z*g.c.y + wv.w*g.d.y;
    float v2 = wv.x*g.a.z + wv.y*g.b.z + wv.z*g.c.z + wv.w*g.d.z;
    float v3 = wv.x*g.a.w + wv.y*g.b.w + wv.z*g.c.w + wv.w*g.d.w;
    ushort4 st; st.x = f2bf(v0); st.y = f2bf(v1); st.z = f2bf(v2); st.w = f2bf(v3);
    *(ushort4*)((char*)Al + (ktc & 1)*2048 + abyte) = st;
  };
  auto issue_B = [&](int ktb){
    const char* bsrc = wpb + (size_t)ktb*16384 + t*16;
    char* bdst = (char*)Bl + (ktb & 3)*16384 + wid*1024;
    GLD(bsrc,                bdst);
    GLD(bsrc + 4096,         bdst + 4096);
    GLD(bsrc + 8192,         bdst + 8192);
    GLD(bsrc + 12288,        bdst + 12288);
  };

  // ---- prologue: B_0,B_1 in flight; g_0,g_1 in flight; A_0 written ----
  issue_B(0);
  issue_B(1);
  asm volatile("" ::: "memory");
  issue_gather(0, gA);
  issue_gather(1, gB);
  convert_write(0, gA);                       // auto-waits g_0 (retires B_0,B_1 too)
  asm volatile("s_waitcnt lgkmcnt(0)" ::: "memory");
  __builtin_amdgcn_sched_barrier(0);
  __builtin_amdgcn_s_barrier();
  __builtin_amdgcn_sched_barrier(0);

  auto body = [&](int kt, Gset& gIss, Gset& gCnv){
    const char* Ac = (const char*)Al + (kt & 1)*2048;
    const char* Bc = (const char*)Bl + (kt & 3)*16384;
    bf16x8 av0 = *(const bf16x8*)(Ac + abr0);
    bf16x8 av1 = *(const bf16x8*)(Ac + abr1);
    bf16x8 bv0 = *(const bf16x8*)(Bc + bbr0);
    bf16x8 bv1 = *(const bf16x8*)(Bc + bbr1);
    bf16x8 bv2 = *(const bf16x8*)(Bc + bbr2);
    bf16x8 bv3 = *(const bf16x8*)(Bc + bbr3);
    if (kt <= 69) issue_B(kt + 2);
    asm volatile("" ::: "memory");            // pin: B GLDs issue before gathers
    if (kt <= 69) issue_gather(kt + 2, gIss);
    acc[0][0] = __builtin_amdgcn_mfma_f32_16x16x32_bf16(av0, bv0, acc[0][0], 0, 0, 0);
    acc[0][1] = __builtin_amdgcn_mfma_f32_16x16x32_bf16(av0, bv1, acc[0][1], 0, 0, 0);
    acc[0][2] = __builtin_amdgcn_mfma_f32_16x16x32_bf16(av0, bv2, acc[0][2], 0, 0, 0);
    acc[0][3] = __builtin_amdgcn_mfma_f32_16x16x32_bf16(av0, bv3, acc[0][3], 0, 0, 0);
    acc[1][0] = __builtin_amdgcn_mfma_f32_16x16x32_bf16(av1, bv0, acc[1][0], 0, 0, 0);
    acc[1][1] = __builtin_amdgcn_mfma_f32_16x16x32_bf16(av1, bv1, acc[1][1], 0, 0, 0);
    acc[1][2] = __builtin_amdgcn_mfma_f32_16x16x32_bf16(av1, bv2, acc[1][2], 0, 0, 0);
    acc[1][3] = __builtin_amdgcn_mfma_f32_16x16x32_bf16(av1, bv3, acc[1][3], 0, 0, 0);
    if (kt <= 70) convert_write(kt + 1, gCnv); // auto-waits gCnv's loads (counted)
    asm volatile("s_waitcnt lgkmcnt(0)" ::: "memory");
    __builtin_amdgcn_sched_barrier(0);
    __builtin_amdgcn_s_barrier();
    __builtin_amdgcn_sched_barrier(0);
  };

  for (int kk = 0; kk < 72; kk += 2){
    body(kk + 0, gA, gB);   // issue g_{kk+2} into gA, convert g_{kk+1} from gB
    body(kk + 1, gB, gA);   // issue g_{kk+3} into gB, convert g_{kk+2} from gA
  }

  // ---- epilogue: direct write to gout ----
#pragma unroll
  for (int mi = 0; mi < 2; ++mi)
#pragma unroll
    for (int ni = 0; ni < 4; ++ni){
      int rr = pbase + mi*16 + (lane>>4)*4;
      int cc = wid*64 + ni*16 + fr;
#pragma unroll
      for (int r = 0; r < 4; ++r)
        gout[(size_t)(rr + r)*CCH + cc] = acc[mi][ni][r];
    }
}

// ---------------- BN stats: per-channel sum & sumsq ----------------
__global__ __launch_bounds__(256) void k_bn_stats(const float* __restrict__ v,
                                                  float* __restrict__ stats){
  int t = threadIdx.x;
  int p0 = blockIdx.x * 128;
  float s = 0.f, ss = 0.f;
  for (int i = 0; i < 128; ++i){
    float x = v[(size_t)(p0 + i)*CCH + t];
    s += x; ss += x*x;
  }
  atomicAdd(&stats[t], s);
  atomicAdd(&stats[CCH + t], ss);
}

// ---------------- BN apply + ReLU (channels-last in/out) ----------------
__global__ __launch_bounds__(256) void k_bn_apply(const float* __restrict__ v,
    const float* __restrict__ stats, const float* __restrict__ g,
    const float* __restrict__ bb, float* __restrict__ y){
  const float inv = 1.f/16384.f;
  for (size_t i = (size_t)blockIdx.x*256 + threadIdx.x; i < (size_t)NPIX*CCH;
       i += (size_t)gridDim.x*256){
    int c = (int)(i & 255);
    float mean = stats[c]*inv;
    float var  = stats[CCH + c]*inv - mean*mean;
    float sc = g[c]*rsqrtf(var + EPSB);
    float sh = bb[c] - mean*sc;
    float val = fmaf(v[i], sc, sh);
    y[i] = val > 0.f ? val : 0.f;
  }
}

// ---------------- final: BN2 + residual + ReLU, transpose to NCHW ----------------
__global__ __launch_bounds__(256) void k_final(const float* __restrict__ v,
    const float* __restrict__ stats, const float* __restrict__ g,
    const float* __restrict__ bb, const float* __restrict__ x,
    float* __restrict__ out){
  __shared__ float tile[64][65];
  int hw0 = blockIdx.x * 64;
  int o0  = blockIdx.y * 64;
  int n   = blockIdx.z;
  int t = threadIdx.x;
  int col = t & 63, rb = t >> 6;
  const float inv = 1.f/16384.f;
#pragma unroll
  for (int r = 0; r < 16; ++r){
    int pl = rb + r*4;
    tile[pl][col] = v[(size_t)(n*HWSZ + hw0 + pl)*CCH + o0 + col];
  }
  __syncthreads();
#pragma unroll
  for (int r = 0; r < 16; ++r){
    int ol = rb + r*4;
    int o = o0 + ol;
    float mean = stats[o]*inv;
    float var  = stats[CCH + o]*inv - mean*mean;
    float sc = g[o]*rsqrtf(var + EPSB);
    float sh = bb[o] - mean*sc;
    size_t gi = (size_t)(n*CCH + o)*HWSZ + hw0 + col;
    float val = fmaf(tile[col][ol], sc, sh) + x[gi];
    out[gi] = val > 0.f ? val : 0.f;
  }
}

extern "C" void kernel_launch(void* const* d_in, const int* in_sizes, int n_in,
                              void* d_out, int out_size, void* d_ws, size_t ws_size,
                              hipStream_t stream){
  const float* x     = (const float*)d_in[0];
  const float* tm1_w = (const float*)d_in[1];
  const float* tm1_b = (const float*)d_in[2];
  const float* tr1_w = (const float*)d_in[3];
  const float* tr1_b = (const float*)d_in[4];
  const float* dcn1_w= (const float*)d_in[5];
  const float* bn1_g = (const float*)d_in[6];
  const float* bn1_b = (const float*)d_in[7];
  const float* tm2_w = (const float*)d_in[8];
  const float* tm2_b = (const float*)d_in[9];
  const float* tr2_w = (const float*)d_in[10];
  const float* tr2_b = (const float*)d_in[11];
  const float* dcn2_w= (const float*)d_in[12];
  const float* bn2_g = (const float*)d_in[13];
  const float* bn2_b = (const float*)d_in[14];
  float* out = (float*)d_out;

  char* ws = (char*)d_ws;
  size_t cursor = 0;
  auto alloc = [&](size_t bytes)->char*{
    char* p = ws + cursor; cursor += (bytes + 255) & ~(size_t)255; return p;
  };
  float* xT    = (float*)alloc((size_t)NPIX*CCH*4);
  float* ybuf  = (float*)alloc((size_t)NPIX*CCH*4);
  float* gout  = (float*)alloc((size_t)NPIX*CCH*4);
  float* offb  = (float*)alloc((size_t)NPIX*9*2*4);
  float* woff1 = (float*)alloc(9*6*CCH*4);
  float* woff2 = (float*)alloc(9*6*CCH*4);
  __hip_bfloat16* wg1 = (__hip_bfloat16*)alloc((size_t)CCH*CK*2);
  __hip_bfloat16* wg2 = (__hip_bfloat16*)alloc((size_t)CCH*CK*2);
  float* stats = (float*)alloc(1024*4);

  hipMemsetAsync(stats, 0, 1024*4, stream);
  k_transpose_in<<<dim3(64,4,4),256,0,stream>>>(x, xT);
  k_woff_perm<<<54,256,0,stream>>>(tm1_w, tr1_w, woff1);
  k_woff_perm<<<54,256,0,stream>>>(tm2_w, tr2_w, woff2);
  k_wgemm_perm<<<2304,256,0,stream>>>(dcn1_w, wg1);
  k_wgemm_perm<<<2304,256,0,stream>>>(dcn2_w, wg2);

  // ---- layer 1 ----
  k_offsets<<<512,256,0,stream>>>(xT, woff1, tm1_b, tr1_b, offb);
  k_dcn<<<512,256,0,stream>>>(xT, offb, wg1, gout);
  k_bn_stats<<<128,256,0,stream>>>(gout, stats);
  k_bn_apply<<<2048,256,0,stream>>>(gout, stats, bn1_g, bn1_b, ybuf);

  // ---- layer 2 ----
  k_offsets<<<512,256,0,stream>>>(ybuf, woff2, tm2_b, tr2_b, offb);
  k_dcn<<<512,256,0,stream>>>(ybuf, offb, wg2, gout);
  k_bn_stats<<<128,256,0,stream>>>(gout, stats + 512);
  k_final<<<dim3(64,4,4),256,0,stream>>>(gout, stats + 512, bn2_g, bn2_b, x, out);
}